// Round 4
// baseline (115.844 us; speedup 1.0000x reference)
//
#include <hip/hip_runtime.h>
#include <hip/hip_bf16.h>
#include <hip/hip_cooperative_groups.h>

namespace cg = cooperative_groups;

typedef short bfrag8 __attribute__((ext_vector_type(8)));
typedef float f32x4v __attribute__((ext_vector_type(4)));
typedef unsigned short U16;
typedef unsigned int U32;

#define NN 4096
#define DD 128

static __device__ __forceinline__ U16 f2bf(float f){
  union { __hip_bfloat16 b; U16 u; } cv;
  cv.b = __float2bfloat16(f);
  return cv.u;
}

// async global->LDS, 16B per lane: lds dest = wave-uniform base + lane*16
#define GLL16(gsrc, ldst) \
  __builtin_amdgcn_global_load_lds((const __attribute__((address_space(1))) unsigned int*)(gsrc), \
                                   (__attribute__((address_space(3))) unsigned int*)(ldst), 16, 0, 0)

// ONE cooperative kernel: 256 blocks x 1024 threads, 128 KB LDS.
// Phase 1: W->LDS + bf16 W^T image (all waves); waves 0-3: affine+GEMM+LN+
//          f1/f2+hTt for this block's 64 rows (LN kept in regs);
//          waves 4-15: pack 32 adj half-rows into bitmasks.
// grid.sync()
// Phase 2: fused att-gen + att@h + elu + residual (R3 k2 structure).
__global__ __launch_bounds__(1024, 4) void kFused(
    const float* __restrict__ x, const int* __restrict__ adj,
    const float* __restrict__ W,
    const float* __restrict__ a1, const float* __restrict__ a2,
    const float* __restrict__ nw, const float* __restrict__ nb,
    const float* __restrict__ gamma, const float* __restrict__ beta,
    U16* __restrict__ hTt, float* __restrict__ f1, float* __restrict__ f2,
    unsigned long long* __restrict__ adjb64, float* __restrict__ out)
{
  __shared__ U16 bt[65536];                  // 128 KB
  const int tid = threadIdx.x;
  const int lane = tid & 63, w = tid >> 6;
  const int l15 = lane & 15, grp = lane >> 4;
  const int bid = blockIdx.x;

  f32x4v hacc[8];                            // phase-1 LN rows (waves 0-3 only)
  #pragma unroll
  for (int i = 0; i < 8; ++i) hacc[i] = (f32x4v){0.f,0.f,0.f,0.f};

  // ================= phase 1 =================
  {
    // (a) stage W (f32 [d][dp]) into LDS upper half, rotated rows (conflict-free)
    float4* ldsF4 = reinterpret_cast<float4*>(bt + 32768);   // bytes 64K..128K
    const float4* W4 = reinterpret_cast<const float4*>(W);
    #pragma unroll
    for (int q = 0; q < 4; ++q){
      int idx4 = q*1024 + tid;               // 4096 float4s
      int d = idx4 >> 5, dp4 = idx4 & 31;
      ldsF4[d*32 + ((dp4 + (d >> 3)) & 31)] = W4[idx4];
    }
    __syncthreads();

    // (b) build bf16 swizzled W^T image in bt[0..16384) shorts:
    // image[dp*128 + sc] = W[d][dp], d = ((((sc>>3)^(dp&15))&15)<<3)|(sc&7)
    const float* ldsF = reinterpret_cast<const float*>(ldsF4);
    #pragma unroll
    for (int k = 0; k < 2; ++k){
      int c = k*1024 + tid;                  // 2048 chunks of 8 shorts
      int dp = c >> 4;
      int d0 = (((c & 15) ^ (dp & 15)) & 15) << 3;
      bfrag8 t;
      #pragma unroll
      for (int e = 0; e < 8; ++e){
        int d = d0 + e;
        t[e] = (short)f2bf(ldsF[d*128 + (((((dp>>2) + (d>>3)) & 31) << 2) | (dp & 3))]);
      }
      *reinterpret_cast<bfrag8*>(bt + c*8) = t;
    }
    __syncthreads();
  }

  if (w < 4){
    // ---------- row compute: 16 rows per wave ----------
    const int rA = bid*64 + w*16 + l15;
    const int nA = rA & 4095;
    const float wgt = nw[nA] + 1.0f, bia = nb[nA];
    const float* xr = x + (size_t)rA*DD;

    #pragma unroll
    for (int ks = 0; ks < 4; ++ks){
      int d8 = ks*32 + grp*8;
      float4 xa = *reinterpret_cast<const float4*>(xr + d8);
      float4 xb = *reinterpret_cast<const float4*>(xr + d8 + 4);
      bfrag8 af;
      af[0] = (short)f2bf(xa.x*wgt + bia);
      af[1] = (short)f2bf(xa.y*wgt + bia);
      af[2] = (short)f2bf(xa.z*wgt + bia);
      af[3] = (short)f2bf(xa.w*wgt + bia);
      af[4] = (short)f2bf(xb.x*wgt + bia);
      af[5] = (short)f2bf(xb.y*wgt + bia);
      af[6] = (short)f2bf(xb.z*wgt + bia);
      af[7] = (short)f2bf(xb.w*wgt + bia);
      #pragma unroll
      for (int nf = 0; nf < 8; ++nf){
        int dp = nf*16 + l15;
        bfrag8 bf = *reinterpret_cast<const bfrag8*>(
            bt + dp*128 + ((((ks*4 + grp)*8)) ^ ((dp&15)<<3)));
        hacc[nf] = __builtin_amdgcn_mfma_f32_16x16x32_bf16(af, bf, hacc[nf], 0, 0, 0);
      }
    }

    float gc[8], bc[8], c1[8], c2[8];
    #pragma unroll
    for (int nf = 0; nf < 8; ++nf){
      int col = nf*16 + l15;
      gc[nf] = gamma[col]; bc[nf] = beta[col];
      c1[nf] = a1[col];    c2[nf] = a2[col];
    }

    // C/D layout: col = lane&15, row = (lane>>4)*4 + r (m89-verified)
    const int rCb = bid*64 + w*16 + grp*4;
    #pragma unroll
    for (int r = 0; r < 4; ++r){
      float s = 0.f, qq = 0.f;
      #pragma unroll
      for (int nf = 0; nf < 8; ++nf){ float v = hacc[nf][r]; s += v; qq += v*v; }
      #pragma unroll
      for (int m = 1; m < 16; m <<= 1){ s += __shfl_xor(s, m); qq += __shfl_xor(qq, m); }
      float mu = s * 0.0078125f;
      float var = fmaxf(qq*0.0078125f - mu*mu, 0.f);
      float rstd = rsqrtf(var + 1e-5f);
      const int rC = rCb + r;
      float p1 = 0.f, p2 = 0.f;
      #pragma unroll
      for (int nf = 0; nf < 8; ++nf){
        float hn = (hacc[nf][r] - mu)*rstd*gc[nf] + bc[nf];
        hacc[nf][r] = hn;                    // stays in regs for the epilogue
        p1 += hn*c1[nf]; p2 += hn*c2[nf];
      }
      #pragma unroll
      for (int m = 1; m < 16; m <<= 1){ p1 += __shfl_xor(p1, m); p2 += __shfl_xor(p2, m); }
      if (l15 == 0){ f1[rC] = p1; f2[rC] = p2; }
    }

    // ---------- wave-local transpose -> hTt (tiled + inverse-swizzled) ----------
    U16* S = bt + 16384 + w*2048;            // bytes 32K..48K, 4 KB per wave
    #pragma unroll
    for (int r = 0; r < 4; ++r)
      #pragma unroll
      for (int nf = 0; nf < 8; ++nf)
        S[(grp*4 + r)*128 + nf*16 + l15] = f2bf(hacc[nf][r]);
    // wave-local: compiler orders ds_write->ds_read by dependence
    #pragma unroll
    for (int dd = 0; dd < 2; ++dd){
      int d = dd*64 + lane;
      #pragma unroll
      for (int u = 0; u < 2; ++u){
        int qc = (2*w + u) ^ (d & 7);
        bfrag8 t;
        #pragma unroll
        for (int e = 0; e < 8; ++e)
          t[e] = (short)S[(u*8 + e)*128 + d];
        *reinterpret_cast<bfrag8*>(hTt + (size_t)bid*8192 + d*64 + qc*8) = t;
      }
    }
  } else {
    // ---------- adj pack: 32 half-rows per block over 12 waves ----------
    const int wq = w - 4;
    for (int c = wq; c < 32; c += 12){
      const int hr = bid*32 + c;
      const int* src = adj + (size_t)hr*2048;
      unsigned long long* dst = adjb64 + (size_t)hr*32;
      #pragma unroll 8
      for (int p = 0; p < 32; ++p){
        unsigned long long m = __ballot(src[p*64 + lane] != 0);
        if (lane == 0) dst[p] = m;
      }
    }
  }

  cg::this_grid().sync();

  // ================= phase 2 =================
  // wave mapping: kq = w>>2, tile = w&3  (so kq==0 waves own the rows whose
  // LN values they computed in phase 1 -> hacc reused in epilogue)
  const int kq = w >> 2, tile = w & 3;
  const int b = bid >> 6;
  const int i0 = (bid & 63)*64 + tile*16;
  const int row = i0 + l15;

  const float CMASK = 0.2f * -9.0e15f;       // leaky(MASK_VAL), exact
  const float A2C   = 0.04f;                 // leaky∘leaky negative slope

  const float f1v = f1[b*NN + row];
  const float* f2b = f2 + b*NN;
  const U32* arow = reinterpret_cast<const U32*>(adjb64) + (size_t)row*128;
  const U16* hTb = hTt + (size_t)b*64*8192;

  const int sub = tile;
  const U16* sbase = hTb + (size_t)kq*16*8192 + sub*2048 + lane*8;

  // prologue: stage s=0 into buf 0
  {
    int dsto = kq*8192 + sub*2048;
    #pragma unroll
    for (int c = 0; c < 4; ++c)
      GLL16(sbase + c*512, &bt[dsto + c*512]);
  }
  float4 cfa0, cfb0, cfa1, cfb1; U32 cw0, cw1;
  {
    int j0 = kq*1024 + grp*8;
    cfa0 = *reinterpret_cast<const float4*>(f2b + j0);
    cfb0 = *reinterpret_cast<const float4*>(f2b + j0 + 4);
    cfa1 = *reinterpret_cast<const float4*>(f2b + j0 + 32);
    cfb1 = *reinterpret_cast<const float4*>(f2b + j0 + 36);
    cw0 = arow[kq*32];
    cw1 = arow[kq*32 + 1];
  }

  f32x4v acc[8] = {};
  __syncthreads();                            // tile 0 staged

  for (int s = 0; s < 16; ++s){
    if (s < 15){                              // issue next tile's staging first
      const U16* gp = sbase + (size_t)(s+1)*8192;
      int dsto = (((s+1)&1)*4 + kq)*8192 + sub*2048;
      #pragma unroll
      for (int c = 0; c < 4; ++c)
        GLL16(gp + c*512, &bt[dsto + c*512]);
    }
    float4 nfa0, nfb0, nfa1, nfb1; U32 nw0, nw1;
    if (s < 15){                              // prefetch next iter's f2 / adj bits
      int j0 = kq*1024 + (s+1)*64 + grp*8;
      nfa0 = *reinterpret_cast<const float4*>(f2b + j0);
      nfb0 = *reinterpret_cast<const float4*>(f2b + j0 + 4);
      nfa1 = *reinterpret_cast<const float4*>(f2b + j0 + 32);
      nfb1 = *reinterpret_cast<const float4*>(f2b + j0 + 36);
      int wi = kq*32 + (s+1)*2;
      nw0 = arow[wi]; nw1 = arow[wi+1];
    }

    const int bbase = ((s&1)*4 + kq)*8192;
    // ---- kc = 0 ----
    {
      U32 byt = (cw0 >> (grp*8)) & 0xffu;
      bfrag8 af;
      float sv, uv;
      sv = f1v + cfa0.x; uv = fmaxf(sv, A2C*sv); af[0] = (short)f2bf((byt & 1u)  ? uv : CMASK);
      sv = f1v + cfa0.y; uv = fmaxf(sv, A2C*sv); af[1] = (short)f2bf((byt & 2u)  ? uv : CMASK);
      sv = f1v + cfa0.z; uv = fmaxf(sv, A2C*sv); af[2] = (short)f2bf((byt & 4u)  ? uv : CMASK);
      sv = f1v + cfa0.w; uv = fmaxf(sv, A2C*sv); af[3] = (short)f2bf((byt & 8u)  ? uv : CMASK);
      sv = f1v + cfb0.x; uv = fmaxf(sv, A2C*sv); af[4] = (short)f2bf((byt & 16u) ? uv : CMASK);
      sv = f1v + cfb0.y; uv = fmaxf(sv, A2C*sv); af[5] = (short)f2bf((byt & 32u) ? uv : CMASK);
      sv = f1v + cfb0.z; uv = fmaxf(sv, A2C*sv); af[6] = (short)f2bf((byt & 64u) ? uv : CMASK);
      sv = f1v + cfb0.w; uv = fmaxf(sv, A2C*sv); af[7] = (short)f2bf((byt & 128u)? uv : CMASK);
      const int cr8 = grp*8;
      #pragma unroll
      for (int nf = 0; nf < 8; ++nf){
        int d = nf*16 + l15;
        bfrag8 bf = *reinterpret_cast<const bfrag8*>(
            bt + bbase + d*64 + (cr8 ^ ((d&7)<<3)));
        acc[nf] = __builtin_amdgcn_mfma_f32_16x16x32_bf16(af, bf, acc[nf], 0, 0, 0);
      }
    }
    // ---- kc = 1 ----
    {
      U32 byt = (cw1 >> (grp*8)) & 0xffu;
      bfrag8 af;
      float sv, uv;
      sv = f1v + cfa1.x; uv = fmaxf(sv, A2C*sv); af[0] = (short)f2bf((byt & 1u)  ? uv : CMASK);
      sv = f1v + cfa1.y; uv = fmaxf(sv, A2C*sv); af[1] = (short)f2bf((byt & 2u)  ? uv : CMASK);
      sv = f1v + cfa1.z; uv = fmaxf(sv, A2C*sv); af[2] = (short)f2bf((byt & 4u)  ? uv : CMASK);
      sv = f1v + cfa1.w; uv = fmaxf(sv, A2C*sv); af[3] = (short)f2bf((byt & 8u)  ? uv : CMASK);
      sv = f1v + cfb1.x; uv = fmaxf(sv, A2C*sv); af[4] = (short)f2bf((byt & 16u) ? uv : CMASK);
      sv = f1v + cfb1.y; uv = fmaxf(sv, A2C*sv); af[5] = (short)f2bf((byt & 32u) ? uv : CMASK);
      sv = f1v + cfb1.z; uv = fmaxf(sv, A2C*sv); af[6] = (short)f2bf((byt & 64u) ? uv : CMASK);
      sv = f1v + cfb1.w; uv = fmaxf(sv, A2C*sv); af[7] = (short)f2bf((byt & 128u)? uv : CMASK);
      const int cr8 = 32 + grp*8;
      #pragma unroll
      for (int nf = 0; nf < 8; ++nf){
        int d = nf*16 + l15;
        bfrag8 bf = *reinterpret_cast<const bfrag8*>(
            bt + bbase + d*64 + (cr8 ^ ((d&7)<<3)));
        acc[nf] = __builtin_amdgcn_mfma_f32_16x16x32_bf16(af, bf, acc[nf], 0, 0, 0);
      }
    }

    __syncthreads();   // all waves done with buf[s&1]; next staging drained here
    cfa0 = nfa0; cfb0 = nfb0; cfa1 = nfa1; cfb1 = nfb1; cw0 = nw0; cw1 = nw1;
  }

  // combine 4 K-quarters through LDS, fused elu+residual epilogue
  float* sc = reinterpret_cast<float*>(bt);   // 3 regions x 8192 f32
  if (kq != 0){
    int rbase = (kq-1)*8192 + tile*2048;
    #pragma unroll
    for (int nf = 0; nf < 8; ++nf)
      #pragma unroll
      for (int r = 0; r < 4; ++r)
        sc[rbase + (grp*4 + r)*128 + nf*16 + l15] = acc[nf][r];
  }
  __syncthreads();
  if (kq == 0){
    #pragma unroll
    for (int nf = 0; nf < 8; ++nf)
      #pragma unroll
      for (int r = 0; r < 4; ++r){
        int off = tile*2048 + (grp*4 + r)*128 + nf*16 + l15;
        float hp = acc[nf][r] + sc[off] + sc[8192 + off] + sc[16384 + off];
        float e = hp > 0.f ? hp : __expf(hp) - 1.f;
        size_t o = ((size_t)b*NN + i0 + grp*4 + r)*DD + nf*16 + l15;
        out[o] = e + hacc[nf][r];             // residual from phase-1 regs
      }
  }
}

extern "C" void kernel_launch(void* const* d_in, const int* in_sizes, int n_in,
                              void* d_out, int out_size, void* d_ws, size_t ws_size,
                              hipStream_t stream) {
  const float* x     = (const float*)d_in[0];
  const int*   adj   = (const int*)  d_in[1];
  const float* W     = (const float*)d_in[2];
  const float* a1    = (const float*)d_in[3];
  const float* a2    = (const float*)d_in[4];
  const float* nw    = (const float*)d_in[5];
  const float* nb    = (const float*)d_in[6];
  const float* gamma = (const float*)d_in[7];
  const float* beta  = (const float*)d_in[8];
  float* out = (float*)d_out;

  char* ws = (char*)d_ws;
  U16*   hTt = (U16*)(ws);                               // 4 MB (tiled)
  float* f1  = (float*)(ws + 4*1024*1024);               // 64 KB
  float* f2  = (float*)(ws + 4*1024*1024 + 64*1024);     // 64 KB
  unsigned long long* adjb64 = (unsigned long long*)(ws + 5*1024*1024); // 2 MB

  void* args[] = {(void*)&x, (void*)&adj, (void*)&W, (void*)&a1, (void*)&a2,
                  (void*)&nw, (void*)&nb, (void*)&gamma, (void*)&beta,
                  (void*)&hTt, (void*)&f1, (void*)&f2, (void*)&adjb64, (void*)&out};
  hipLaunchCooperativeKernel((void*)kFused, dim3(256), dim3(1024), args, 0, stream);
}

// Round 5
// 77.635 us; speedup vs baseline: 1.4922x; 1.4922x over previous
//
#include <hip/hip_runtime.h>
#include <hip/hip_bf16.h>

typedef short bfrag8 __attribute__((ext_vector_type(8)));
typedef float f32x4v __attribute__((ext_vector_type(4)));
typedef unsigned short U16;
typedef unsigned int U32;

#define NN 4096
#define DD 128

static __device__ __forceinline__ U16 f2bf(float f){
  union { __hip_bfloat16 b; U16 u; } cv;
  cv.b = __float2bfloat16(f);
  return cv.u;
}

static __device__ __forceinline__ float bf2f(U16 u){
  union { float f; U32 u; } cv;
  cv.u = ((U32)u) << 16;
  return cv.f;
}

// async global->LDS, 16B per lane: lds dest = wave-uniform base + lane*16
#define GLL16(gsrc, ldst) \
  __builtin_amdgcn_global_load_lds((const __attribute__((address_space(1))) unsigned int*)(gsrc), \
                                   (__attribute__((address_space(3))) unsigned int*)(ldst), 16, 0, 0)

// ---------------- kernel 0: WT[dp][d] = bf16(W[d][dp]) ----------------
__global__ void k0_wt(const float* __restrict__ W, U16* __restrict__ WT){
  int i = blockIdx.x*256 + threadIdx.x;      // i = d*128 + dp
  int d = i >> 7, dp = i & 127;
  WT[dp*128 + d] = f2bf(W[i]);
}

// ---------------- merged pre-pass ----------------
// blocks [0,256): x2 = x*(nw+1)+nb; h = LN(x2@W) via MFMA; writes h_lnB (bf16),
//                 hTt (bf16 tiled+inverse-swizzled), f1/f2.
// blocks [256,2304): pack adj (int 0/1) into 64-bit masks (ballot). Independent
//                 work in the same dispatch -> overlaps the compute blocks.
__global__ __launch_bounds__(256) void kB_prep(
    const float* __restrict__ x, const U16* __restrict__ WT,
    const int* __restrict__ adj,
    const float* __restrict__ nw, const float* __restrict__ nb,
    const float* __restrict__ gamma, const float* __restrict__ beta,
    const float* __restrict__ a1, const float* __restrict__ a2,
    U16* __restrict__ h_lnB, U16* __restrict__ hTt,
    float* __restrict__ f1, float* __restrict__ f2,
    unsigned long long* __restrict__ adjb64)
{
  __shared__ U16 lds[16384];                 // 32 KB: WT (swizzled), later hb[64][128]
  const int tid = threadIdx.x;
  const int lane = tid & 63, w = tid >> 6;

  if (blockIdx.x >= 256){
    // ---------- adj pack ----------
    const int Wv = (blockIdx.x - 256)*4 + w;   // wave id, 8192 total
    const int* src = adj + (size_t)Wv*2048;
    unsigned long long* dst = adjb64 + (size_t)Wv*32;
    #pragma unroll 8
    for (int p = 0; p < 32; ++p){
      int v = src[p*64 + lane];
      unsigned long long m = __ballot(v != 0);
      if (lane == 0) dst[p] = m;
    }
    return;
  }

  const int l15 = lane & 15, grp = lane >> 4;

  // stage WT into LDS with XOR swizzle (proven R2 pattern)
  #pragma unroll
  for (int q = 0; q < 8; ++q){
    int cid = q*256 + tid;
    int dp = cid >> 4, c = cid & 15;
    *reinterpret_cast<int4*>(lds + dp*128 + ((c*8) ^ ((dp&15)<<3))) =
        *reinterpret_cast<const int4*>(WT + cid*8);
  }
  __syncthreads();

  const int rA = blockIdx.x*64 + w*16 + l15;
  const int nA = rA & 4095;
  const float wgt = nw[nA] + 1.0f, bia = nb[nA];
  const float* xr = x + (size_t)rA*DD;

  f32x4v acc[8] = {};
  #pragma unroll
  for (int ks = 0; ks < 4; ++ks){
    int d8 = ks*32 + grp*8;
    float4 xa = *reinterpret_cast<const float4*>(xr + d8);
    float4 xb = *reinterpret_cast<const float4*>(xr + d8 + 4);
    bfrag8 af;
    af[0] = (short)f2bf(xa.x*wgt + bia);
    af[1] = (short)f2bf(xa.y*wgt + bia);
    af[2] = (short)f2bf(xa.z*wgt + bia);
    af[3] = (short)f2bf(xa.w*wgt + bia);
    af[4] = (short)f2bf(xb.x*wgt + bia);
    af[5] = (short)f2bf(xb.y*wgt + bia);
    af[6] = (short)f2bf(xb.z*wgt + bia);
    af[7] = (short)f2bf(xb.w*wgt + bia);
    #pragma unroll
    for (int nf = 0; nf < 8; ++nf){
      int dp = nf*16 + l15;
      bfrag8 bf = *reinterpret_cast<const bfrag8*>(
          lds + dp*128 + ((((ks*4 + grp)*8)) ^ ((dp&15)<<3)));
      acc[nf] = __builtin_amdgcn_mfma_f32_16x16x32_bf16(af, bf, acc[nf], 0, 0, 0);
    }
  }

  float gc[8], bc[8], c1[8], c2[8];
  #pragma unroll
  for (int nf = 0; nf < 8; ++nf){
    int col = nf*16 + l15;
    gc[nf] = gamma[col]; bc[nf] = beta[col];
    c1[nf] = a1[col];    c2[nf] = a2[col];
  }

  // C/D layout: col = lane&15, row = (lane>>4)*4 + r (m89-verified)
  const int rCb = blockIdx.x*64 + w*16 + grp*4;
  #pragma unroll
  for (int r = 0; r < 4; ++r){
    float s = 0.f, qq = 0.f;
    #pragma unroll
    for (int nf = 0; nf < 8; ++nf){ float v = acc[nf][r]; s += v; qq += v*v; }
    #pragma unroll
    for (int m = 1; m < 16; m <<= 1){ s += __shfl_xor(s, m); qq += __shfl_xor(qq, m); }
    float mu = s * 0.0078125f;
    float var = fmaxf(qq*0.0078125f - mu*mu, 0.f);
    float rstd = rsqrtf(var + 1e-5f);
    const int rC = rCb + r;
    float p1 = 0.f, p2 = 0.f;
    #pragma unroll
    for (int nf = 0; nf < 8; ++nf){
      float hn = (acc[nf][r] - mu)*rstd*gc[nf] + bc[nf];
      acc[nf][r] = hn;
      h_lnB[(size_t)rC*DD + nf*16 + l15] = f2bf(hn);
      p1 += hn*c1[nf]; p2 += hn*c2[nf];
    }
    #pragma unroll
    for (int m = 1; m < 16; m <<= 1){ p1 += __shfl_xor(p1, m); p2 += __shfl_xor(p2, m); }
    if (l15 == 0){ f1[rC] = p1; f2[rC] = p2; }
  }

  __syncthreads();   // WT no longer needed; reuse LDS as hb[64 n][128 d]
  #pragma unroll
  for (int r = 0; r < 4; ++r)
    #pragma unroll
    for (int nf = 0; nf < 8; ++nf)
      lds[(w*16 + grp*4 + r)*128 + nf*16 + l15] = f2bf(acc[nf][r]);
  __syncthreads();

  // tiled + inverse-swizzled write: chunk (d,qc) holds h[n=(qc^(d&7))*8+e][d],
  // so k2 stages linearly (global_load_lds) and reads with the XOR swizzle.
  {
    const int r0 = blockIdx.x*64;
    const int tilei = (r0 >> 12)*64 + ((r0 >> 6) & 63);
    U16* dstt = hTt + (size_t)tilei*8192;
    #pragma unroll
    for (int k = 0; k < 4; ++k){
      int cid = tid*4 + k;             // 0..1023
      int d = cid >> 3, qc = cid & 7;
      int nl = (qc ^ (d & 7)) * 8;
      bfrag8 t;
      #pragma unroll
      for (int e = 0; e < 8; ++e)
        t[e] = (short)lds[(nl + e)*128 + d];
      *reinterpret_cast<bfrag8*>(dstt + d*64 + qc*8) = t;
    }
  }
}

// ---------------- kernel 2: fused att-gen + att@h + elu + residual ----------------
// grid 256: block = (batch b, 64 i-rows); 16 waves = 4 tiles(16 rows) x 4 K-quarters.
// B-tiles staged via global_load_lds from tiled hTt, double-buffered 128KB LDS.
__global__ __launch_bounds__(1024) void k2_main(
    const U32* __restrict__ adjb, const U16* __restrict__ hTt,
    const float* __restrict__ f1, const float* __restrict__ f2,
    const U16* __restrict__ h_lnB, float* __restrict__ out)
{
  __shared__ U16 bt[65536];                  // 128 KB: [buf 2][kq 4][8192]
  const int tid = threadIdx.x;
  const int lane = tid & 63, w = tid >> 6;
  const int kq = w & 3, tile = w >> 2;
  const int l15 = lane & 15, grp = lane >> 4;
  const int b = blockIdx.x >> 6;
  const int i0 = (blockIdx.x & 63)*64 + tile*16;
  const int row = i0 + l15;

  const float CMASK = 0.2f * -9.0e15f;       // leaky(MASK_VAL), exact
  const float A2C   = 0.04f;                 // leaky∘leaky negative slope

  const float f1v = f1[b*NN + row];
  const float* f2b = f2 + b*NN;
  const U32* arow = adjb + (size_t)row*128;
  const U16* hTb = hTt + (size_t)b*64*8192;

  // staging: wave w stages quarter kq's sub-block sub = tile (4KB = 4 x GLL16)
  const int sub = tile;
  const U16* sbase = hTb + (size_t)kq*16*8192 + sub*2048 + lane*8;

  // prologue: stage s=0 into buf 0
  {
    int dsto = kq*8192 + sub*2048;
    #pragma unroll
    for (int c = 0; c < 4; ++c)
      GLL16(sbase + c*512, &bt[dsto + c*512]);
  }
  // prologue: regs for s=0
  float4 cfa0, cfb0, cfa1, cfb1; U32 cw0, cw1;
  {
    int j0 = kq*1024 + grp*8;
    cfa0 = *reinterpret_cast<const float4*>(f2b + j0);
    cfb0 = *reinterpret_cast<const float4*>(f2b + j0 + 4);
    cfa1 = *reinterpret_cast<const float4*>(f2b + j0 + 32);
    cfb1 = *reinterpret_cast<const float4*>(f2b + j0 + 36);
    cw0 = arow[kq*32];
    cw1 = arow[kq*32 + 1];
  }

  f32x4v acc[8] = {};
  __syncthreads();                            // tile 0 staged

  for (int s = 0; s < 16; ++s){
    if (s < 15){                              // issue next tile's staging first
      const U16* gp = sbase + (size_t)(s+1)*8192;
      int dsto = (((s+1)&1)*4 + kq)*8192 + sub*2048;
      #pragma unroll
      for (int c = 0; c < 4; ++c)
        GLL16(gp + c*512, &bt[dsto + c*512]);
    }
    float4 nfa0, nfb0, nfa1, nfb1; U32 nw0, nw1;
    if (s < 15){                              // prefetch next iter's f2 / adj bits
      int j0 = kq*1024 + (s+1)*64 + grp*8;
      nfa0 = *reinterpret_cast<const float4*>(f2b + j0);
      nfb0 = *reinterpret_cast<const float4*>(f2b + j0 + 4);
      nfa1 = *reinterpret_cast<const float4*>(f2b + j0 + 32);
      nfb1 = *reinterpret_cast<const float4*>(f2b + j0 + 36);
      int wi = kq*32 + (s+1)*2;
      nw0 = arow[wi]; nw1 = arow[wi+1];
    }

    const int bbase = ((s&1)*4 + kq)*8192;
    // ---- kc = 0 ----
    {
      U32 byt = (cw0 >> (grp*8)) & 0xffu;
      bfrag8 af;
      float sv, uv;
      sv = f1v + cfa0.x; uv = fmaxf(sv, A2C*sv); af[0] = (short)f2bf((byt & 1u)  ? uv : CMASK);
      sv = f1v + cfa0.y; uv = fmaxf(sv, A2C*sv); af[1] = (short)f2bf((byt & 2u)  ? uv : CMASK);
      sv = f1v + cfa0.z; uv = fmaxf(sv, A2C*sv); af[2] = (short)f2bf((byt & 4u)  ? uv : CMASK);
      sv = f1v + cfa0.w; uv = fmaxf(sv, A2C*sv); af[3] = (short)f2bf((byt & 8u)  ? uv : CMASK);
      sv = f1v + cfb0.x; uv = fmaxf(sv, A2C*sv); af[4] = (short)f2bf((byt & 16u) ? uv : CMASK);
      sv = f1v + cfb0.y; uv = fmaxf(sv, A2C*sv); af[5] = (short)f2bf((byt & 32u) ? uv : CMASK);
      sv = f1v + cfb0.z; uv = fmaxf(sv, A2C*sv); af[6] = (short)f2bf((byt & 64u) ? uv : CMASK);
      sv = f1v + cfb0.w; uv = fmaxf(sv, A2C*sv); af[7] = (short)f2bf((byt & 128u)? uv : CMASK);
      const int cr8 = grp*8;
      #pragma unroll
      for (int nf = 0; nf < 8; ++nf){
        int d = nf*16 + l15;
        bfrag8 bf = *reinterpret_cast<const bfrag8*>(
            bt + bbase + d*64 + (cr8 ^ ((d&7)<<3)));
        acc[nf] = __builtin_amdgcn_mfma_f32_16x16x32_bf16(af, bf, acc[nf], 0, 0, 0);
      }
    }
    // ---- kc = 1 ----
    {
      U32 byt = (cw1 >> (grp*8)) & 0xffu;
      bfrag8 af;
      float sv, uv;
      sv = f1v + cfa1.x; uv = fmaxf(sv, A2C*sv); af[0] = (short)f2bf((byt & 1u)  ? uv : CMASK);
      sv = f1v + cfa1.y; uv = fmaxf(sv, A2C*sv); af[1] = (short)f2bf((byt & 2u)  ? uv : CMASK);
      sv = f1v + cfa1.z; uv = fmaxf(sv, A2C*sv); af[2] = (short)f2bf((byt & 4u)  ? uv : CMASK);
      sv = f1v + cfa1.w; uv = fmaxf(sv, A2C*sv); af[3] = (short)f2bf((byt & 8u)  ? uv : CMASK);
      sv = f1v + cfb1.x; uv = fmaxf(sv, A2C*sv); af[4] = (short)f2bf((byt & 16u) ? uv : CMASK);
      sv = f1v + cfb1.y; uv = fmaxf(sv, A2C*sv); af[5] = (short)f2bf((byt & 32u) ? uv : CMASK);
      sv = f1v + cfb1.z; uv = fmaxf(sv, A2C*sv); af[6] = (short)f2bf((byt & 64u) ? uv : CMASK);
      sv = f1v + cfb1.w; uv = fmaxf(sv, A2C*sv); af[7] = (short)f2bf((byt & 128u)? uv : CMASK);
      const int cr8 = 32 + grp*8;
      #pragma unroll
      for (int nf = 0; nf < 8; ++nf){
        int d = nf*16 + l15;
        bfrag8 bf = *reinterpret_cast<const bfrag8*>(
            bt + bbase + d*64 + (cr8 ^ ((d&7)<<3)));
        acc[nf] = __builtin_amdgcn_mfma_f32_16x16x32_bf16(af, bf, acc[nf], 0, 0, 0);
      }
    }

    __syncthreads();   // all waves done with buf[s&1]; next staging drained here
    cfa0 = nfa0; cfb0 = nfb0; cfa1 = nfa1; cfb1 = nfb1; cw0 = nw0; cw1 = nw1;
  }

  // combine 4 K-quarters through LDS (reuse bt as f32 scratch), fused epilogue
  float* sc = reinterpret_cast<float*>(bt);   // 3 regions x 8192 f32
  if (kq != 0){
    int rbase = (kq-1)*8192 + tile*2048;
    #pragma unroll
    for (int nf = 0; nf < 8; ++nf)
      #pragma unroll
      for (int r = 0; r < 4; ++r)
        sc[rbase + (grp*4 + r)*128 + nf*16 + l15] = acc[nf][r];
  }
  __syncthreads();
  if (kq == 0){
    #pragma unroll
    for (int nf = 0; nf < 8; ++nf)
      #pragma unroll
      for (int r = 0; r < 4; ++r){
        int off = tile*2048 + (grp*4 + r)*128 + nf*16 + l15;
        float hp = acc[nf][r] + sc[off] + sc[8192 + off] + sc[16384 + off];
        float e = hp > 0.f ? hp : __expf(hp) - 1.f;
        size_t o = ((size_t)b*NN + i0 + grp*4 + r)*DD + nf*16 + l15;
        out[o] = e + bf2f(h_lnB[o]);
      }
  }
}

extern "C" void kernel_launch(void* const* d_in, const int* in_sizes, int n_in,
                              void* d_out, int out_size, void* d_ws, size_t ws_size,
                              hipStream_t stream) {
  const float* x     = (const float*)d_in[0];
  const int*   adj   = (const int*)  d_in[1];
  const float* W     = (const float*)d_in[2];
  const float* a1    = (const float*)d_in[3];
  const float* a2    = (const float*)d_in[4];
  const float* nw    = (const float*)d_in[5];
  const float* nb    = (const float*)d_in[6];
  const float* gamma = (const float*)d_in[7];
  const float* beta  = (const float*)d_in[8];
  float* out = (float*)d_out;

  char* ws = (char*)d_ws;
  U16*   h_lnB = (U16*)(ws);                            // 4 MB
  U16*   hTt   = (U16*)(ws + 4*1024*1024);              // 4 MB (tiled)
  float* f1    = (float*)(ws + 8*1024*1024);            // 64 KB
  float* f2    = (float*)(ws + 8*1024*1024 + 64*1024);  // 64 KB
  U16*   WT    = (U16*)(ws + 8*1024*1024 + 128*1024);   // 32 KB
  unsigned long long* adjb64 = (unsigned long long*)(ws + 9*1024*1024); // 2 MB

  k0_wt  <<<dim3(64),   dim3(256), 0, stream>>>(W, WT);
  kB_prep<<<dim3(2304), dim3(256), 0, stream>>>(x, WT, adj, nw, nb, gamma, beta,
                                                a1, a2, h_lnB, hTt, f1, f2, adjb64);
  k2_main<<<dim3(256),  dim3(1024), 0, stream>>>((const U32*)adjb64, hTt, f1, f2,
                                                 h_lnB, out);
}

// Round 6
// 66.730 us; speedup vs baseline: 1.7360x; 1.1634x over previous
//
#include <hip/hip_runtime.h>
#include <hip/hip_bf16.h>

typedef short bfrag8 __attribute__((ext_vector_type(8)));
typedef float f32x4v __attribute__((ext_vector_type(4)));
typedef unsigned short U16;
typedef unsigned int U32;

#define NN 4096
#define DD 128

static __device__ __forceinline__ U16 f2bf(float f){
  union { __hip_bfloat16 b; U16 u; } cv;
  cv.b = __float2bfloat16(f);
  return cv.u;
}

static __device__ __forceinline__ float bf2f(U16 u){
  union { float f; U32 u; } cv;
  cv.u = ((U32)u) << 16;
  return cv.f;
}

// async global->LDS, 16B per lane: lds dest = wave-uniform base + lane*16
#define GLL16(gsrc, ldst) \
  __builtin_amdgcn_global_load_lds((const __attribute__((address_space(1))) unsigned int*)(gsrc), \
                                   (__attribute__((address_space(3))) unsigned int*)(ldst), 16, 0, 0)

// ---------------- kernel 0: WT[dp][d] = bf16(W[d][dp]) ----------------
__global__ void k0_wt(const float* __restrict__ W, U16* __restrict__ WT){
  int i = blockIdx.x*256 + threadIdx.x;      // i = d*128 + dp
  int d = i >> 7, dp = i & 127;
  WT[dp*128 + d] = f2bf(W[i]);
}

// ---------------- kernel 0b: pack adj -> bitmask, one u32 word/thread ----------------
// adjb[row*128 + g] bit j = adj[row][g*32 + j] != 0.
// Each thread reads its own 128B line (8 independent int4 loads) -> no cross-lane
// ops, no dependent chains, coalesced u32 stores.
__global__ __launch_bounds__(256) void k0b_pack(const int* __restrict__ adj,
                                                U32* __restrict__ adjb){
  int gid = blockIdx.x*256 + threadIdx.x;    // 524288 threads
  const int4* src = reinterpret_cast<const int4*>(adj) + (size_t)gid*8;
  int4 v[8];
  #pragma unroll
  for (int c = 0; c < 8; ++c) v[c] = src[c];
  U32 m = 0;
  #pragma unroll
  for (int c = 0; c < 8; ++c){
    m |= (v[c].x != 0 ? 1u : 0u) << (c*4);
    m |= (v[c].y != 0 ? 2u : 0u) << (c*4);
    m |= (v[c].z != 0 ? 4u : 0u) << (c*4);
    m |= (v[c].w != 0 ? 8u : 0u) << (c*4);
  }
  adjb[gid] = m;
}

// ---------------- kernel 1: x2 = x*(nw+1)+nb; h = LN(x2@W) via MFMA;
// writes h_lnB (bf16), hTt (bf16 tiled+inverse-swizzled), f1/f2 ----------------
__global__ __launch_bounds__(256) void k1_prep(
    const float* __restrict__ x, const U16* __restrict__ WT,
    const float* __restrict__ nw, const float* __restrict__ nb,
    const float* __restrict__ gamma, const float* __restrict__ beta,
    const float* __restrict__ a1, const float* __restrict__ a2,
    U16* __restrict__ h_lnB, U16* __restrict__ hTt,
    float* __restrict__ f1, float* __restrict__ f2)
{
  __shared__ U16 lds[16384];                 // 32 KB: WT (swizzled), later hb[64][128]
  const int tid = threadIdx.x;
  const int lane = tid & 63, w = tid >> 6;
  const int l15 = lane & 15, grp = lane >> 4;

  // stage WT into LDS with XOR swizzle (proven R2 pattern)
  #pragma unroll
  for (int q = 0; q < 8; ++q){
    int cid = q*256 + tid;
    int dp = cid >> 4, c = cid & 15;
    *reinterpret_cast<int4*>(lds + dp*128 + ((c*8) ^ ((dp&15)<<3))) =
        *reinterpret_cast<const int4*>(WT + cid*8);
  }
  __syncthreads();

  const int rA = blockIdx.x*64 + w*16 + l15;
  const int nA = rA & 4095;
  const float wgt = nw[nA] + 1.0f, bia = nb[nA];
  const float* xr = x + (size_t)rA*DD;

  f32x4v acc[8] = {};
  #pragma unroll
  for (int ks = 0; ks < 4; ++ks){
    int d8 = ks*32 + grp*8;
    float4 xa = *reinterpret_cast<const float4*>(xr + d8);
    float4 xb = *reinterpret_cast<const float4*>(xr + d8 + 4);
    bfrag8 af;
    af[0] = (short)f2bf(xa.x*wgt + bia);
    af[1] = (short)f2bf(xa.y*wgt + bia);
    af[2] = (short)f2bf(xa.z*wgt + bia);
    af[3] = (short)f2bf(xa.w*wgt + bia);
    af[4] = (short)f2bf(xb.x*wgt + bia);
    af[5] = (short)f2bf(xb.y*wgt + bia);
    af[6] = (short)f2bf(xb.z*wgt + bia);
    af[7] = (short)f2bf(xb.w*wgt + bia);
    #pragma unroll
    for (int nf = 0; nf < 8; ++nf){
      int dp = nf*16 + l15;
      bfrag8 bf = *reinterpret_cast<const bfrag8*>(
          lds + dp*128 + ((((ks*4 + grp)*8)) ^ ((dp&15)<<3)));
      acc[nf] = __builtin_amdgcn_mfma_f32_16x16x32_bf16(af, bf, acc[nf], 0, 0, 0);
    }
  }

  float gc[8], bc[8], c1[8], c2[8];
  #pragma unroll
  for (int nf = 0; nf < 8; ++nf){
    int col = nf*16 + l15;
    gc[nf] = gamma[col]; bc[nf] = beta[col];
    c1[nf] = a1[col];    c2[nf] = a2[col];
  }

  // C/D layout: col = lane&15, row = (lane>>4)*4 + r (m89-verified)
  const int rCb = blockIdx.x*64 + w*16 + grp*4;
  #pragma unroll
  for (int r = 0; r < 4; ++r){
    float s = 0.f, qq = 0.f;
    #pragma unroll
    for (int nf = 0; nf < 8; ++nf){ float v = acc[nf][r]; s += v; qq += v*v; }
    #pragma unroll
    for (int m = 1; m < 16; m <<= 1){ s += __shfl_xor(s, m); qq += __shfl_xor(qq, m); }
    float mu = s * 0.0078125f;
    float var = fmaxf(qq*0.0078125f - mu*mu, 0.f);
    float rstd = rsqrtf(var + 1e-5f);
    const int rC = rCb + r;
    float p1 = 0.f, p2 = 0.f;
    #pragma unroll
    for (int nf = 0; nf < 8; ++nf){
      float hn = (acc[nf][r] - mu)*rstd*gc[nf] + bc[nf];
      acc[nf][r] = hn;
      h_lnB[(size_t)rC*DD + nf*16 + l15] = f2bf(hn);
      p1 += hn*c1[nf]; p2 += hn*c2[nf];
    }
    #pragma unroll
    for (int m = 1; m < 16; m <<= 1){ p1 += __shfl_xor(p1, m); p2 += __shfl_xor(p2, m); }
    if (l15 == 0){ f1[rC] = p1; f2[rC] = p2; }
  }

  __syncthreads();   // WT no longer needed; reuse LDS as hb[64 n][128 d]
  #pragma unroll
  for (int r = 0; r < 4; ++r)
    #pragma unroll
    for (int nf = 0; nf < 8; ++nf)
      lds[(w*16 + grp*4 + r)*128 + nf*16 + l15] = f2bf(acc[nf][r]);
  __syncthreads();

  // tiled + inverse-swizzled write: chunk (d,qc) holds h[n=(qc^(d&7))*8+e][d],
  // so k2 stages linearly (global_load_lds) and reads with the XOR swizzle.
  {
    const int r0 = blockIdx.x*64;
    const int tilei = (r0 >> 12)*64 + ((r0 >> 6) & 63);
    U16* dstt = hTt + (size_t)tilei*8192;
    #pragma unroll
    for (int k = 0; k < 4; ++k){
      int cid = tid*4 + k;             // 0..1023
      int d = cid >> 3, qc = cid & 7;
      int nl = (qc ^ (d & 7)) * 8;
      bfrag8 t;
      #pragma unroll
      for (int e = 0; e < 8; ++e)
        t[e] = (short)lds[(nl + e)*128 + d];
      *reinterpret_cast<bfrag8*>(dstt + d*64 + qc*8) = t;
    }
  }
}

// ---------------- kernel 2: fused att-gen + att@h + elu + residual ----------------
// grid 256: block = (batch b, 64 i-rows); 16 waves = 4 tiles(16 rows) x 4 K-quarters.
// B-tiles staged via global_load_lds from tiled hTt, double-buffered 128KB LDS.
__global__ __launch_bounds__(1024) void k2_main(
    const U32* __restrict__ adjb, const U16* __restrict__ hTt,
    const float* __restrict__ f1, const float* __restrict__ f2,
    const U16* __restrict__ h_lnB, float* __restrict__ out)
{
  __shared__ U16 bt[32768*2];                // 128 KB: [buf 2][kq 4][8192]
  const int tid = threadIdx.x;
  const int lane = tid & 63, w = tid >> 6;
  const int kq = w & 3, tile = w >> 2;
  const int l15 = lane & 15, grp = lane >> 4;
  const int b = blockIdx.x >> 6;
  const int i0 = (blockIdx.x & 63)*64 + tile*16;
  const int row = i0 + l15;

  const float CMASK = 0.2f * -9.0e15f;       // leaky(MASK_VAL), exact
  const float A2C   = 0.04f;                 // leaky∘leaky negative slope

  const float f1v = f1[b*NN + row];
  const float* f2b = f2 + b*NN;
  const U32* arow = adjb + (size_t)row*128;
  const U16* hTb = hTt + (size_t)b*64*8192;

  // staging: wave w stages quarter kq's sub-block sub = tile (4KB = 4 x GLL16)
  const int sub = tile;
  const U16* sbase = hTb + (size_t)kq*16*8192 + sub*2048 + lane*8;

  // prologue: stage s=0 into buf 0
  {
    int dsto = kq*8192 + sub*2048;
    #pragma unroll
    for (int c = 0; c < 4; ++c)
      GLL16(sbase + c*512, &bt[dsto + c*512]);
  }
  // prologue: regs for s=0
  float4 cfa0, cfb0, cfa1, cfb1; U32 cw0, cw1;
  {
    int j0 = kq*1024 + grp*8;
    cfa0 = *reinterpret_cast<const float4*>(f2b + j0);
    cfb0 = *reinterpret_cast<const float4*>(f2b + j0 + 4);
    cfa1 = *reinterpret_cast<const float4*>(f2b + j0 + 32);
    cfb1 = *reinterpret_cast<const float4*>(f2b + j0 + 36);
    cw0 = arow[kq*32];
    cw1 = arow[kq*32 + 1];
  }

  f32x4v acc[8] = {};
  __syncthreads();                            // tile 0 staged

  for (int s = 0; s < 16; ++s){
    if (s < 15){                              // issue next tile's staging first
      const U16* gp = sbase + (size_t)(s+1)*8192;
      int dsto = (((s+1)&1)*4 + kq)*8192 + sub*2048;
      #pragma unroll
      for (int c = 0; c < 4; ++c)
        GLL16(gp + c*512, &bt[dsto + c*512]);
    }
    float4 nfa0, nfb0, nfa1, nfb1; U32 nw0, nw1;
    if (s < 15){                              // prefetch next iter's f2 / adj bits
      int j0 = kq*1024 + (s+1)*64 + grp*8;
      nfa0 = *reinterpret_cast<const float4*>(f2b + j0);
      nfb0 = *reinterpret_cast<const float4*>(f2b + j0 + 4);
      nfa1 = *reinterpret_cast<const float4*>(f2b + j0 + 32);
      nfb1 = *reinterpret_cast<const float4*>(f2b + j0 + 36);
      int wi = kq*32 + (s+1)*2;
      nw0 = arow[wi]; nw1 = arow[wi+1];
    }

    const int bbase = ((s&1)*4 + kq)*8192;
    // ---- kc = 0 ----
    {
      U32 byt = (cw0 >> (grp*8)) & 0xffu;
      bfrag8 af;
      float sv, uv;
      sv = f1v + cfa0.x; uv = fmaxf(sv, A2C*sv); af[0] = (short)f2bf((byt & 1u)  ? uv : CMASK);
      sv = f1v + cfa0.y; uv = fmaxf(sv, A2C*sv); af[1] = (short)f2bf((byt & 2u)  ? uv : CMASK);
      sv = f1v + cfa0.z; uv = fmaxf(sv, A2C*sv); af[2] = (short)f2bf((byt & 4u)  ? uv : CMASK);
      sv = f1v + cfa0.w; uv = fmaxf(sv, A2C*sv); af[3] = (short)f2bf((byt & 8u)  ? uv : CMASK);
      sv = f1v + cfb0.x; uv = fmaxf(sv, A2C*sv); af[4] = (short)f2bf((byt & 16u) ? uv : CMASK);
      sv = f1v + cfb0.y; uv = fmaxf(sv, A2C*sv); af[5] = (short)f2bf((byt & 32u) ? uv : CMASK);
      sv = f1v + cfb0.z; uv = fmaxf(sv, A2C*sv); af[6] = (short)f2bf((byt & 64u) ? uv : CMASK);
      sv = f1v + cfb0.w; uv = fmaxf(sv, A2C*sv); af[7] = (short)f2bf((byt & 128u)? uv : CMASK);
      const int cr8 = grp*8;
      #pragma unroll
      for (int nf = 0; nf < 8; ++nf){
        int d = nf*16 + l15;
        bfrag8 bf = *reinterpret_cast<const bfrag8*>(
            bt + bbase + d*64 + (cr8 ^ ((d&7)<<3)));
        acc[nf] = __builtin_amdgcn_mfma_f32_16x16x32_bf16(af, bf, acc[nf], 0, 0, 0);
      }
    }
    // ---- kc = 1 ----
    {
      U32 byt = (cw1 >> (grp*8)) & 0xffu;
      bfrag8 af;
      float sv, uv;
      sv = f1v + cfa1.x; uv = fmaxf(sv, A2C*sv); af[0] = (short)f2bf((byt & 1u)  ? uv : CMASK);
      sv = f1v + cfa1.y; uv = fmaxf(sv, A2C*sv); af[1] = (short)f2bf((byt & 2u)  ? uv : CMASK);
      sv = f1v + cfa1.z; uv = fmaxf(sv, A2C*sv); af[2] = (short)f2bf((byt & 4u)  ? uv : CMASK);
      sv = f1v + cfa1.w; uv = fmaxf(sv, A2C*sv); af[3] = (short)f2bf((byt & 8u)  ? uv : CMASK);
      sv = f1v + cfb1.x; uv = fmaxf(sv, A2C*sv); af[4] = (short)f2bf((byt & 16u) ? uv : CMASK);
      sv = f1v + cfb1.y; uv = fmaxf(sv, A2C*sv); af[5] = (short)f2bf((byt & 32u) ? uv : CMASK);
      sv = f1v + cfb1.z; uv = fmaxf(sv, A2C*sv); af[6] = (short)f2bf((byt & 64u) ? uv : CMASK);
      sv = f1v + cfb1.w; uv = fmaxf(sv, A2C*sv); af[7] = (short)f2bf((byt & 128u)? uv : CMASK);
      const int cr8 = 32 + grp*8;
      #pragma unroll
      for (int nf = 0; nf < 8; ++nf){
        int d = nf*16 + l15;
        bfrag8 bf = *reinterpret_cast<const bfrag8*>(
            bt + bbase + d*64 + (cr8 ^ ((d&7)<<3)));
        acc[nf] = __builtin_amdgcn_mfma_f32_16x16x32_bf16(af, bf, acc[nf], 0, 0, 0);
      }
    }

    __syncthreads();   // all waves done with buf[s&1]; next staging drained here
    cfa0 = nfa0; cfb0 = nfb0; cfa1 = nfa1; cfb1 = nfb1; cw0 = nw0; cw1 = nw1;
  }

  // combine 4 K-quarters through LDS (reuse bt as f32 scratch), fused epilogue
  float* sc = reinterpret_cast<float*>(bt);   // 3 regions x 8192 f32
  if (kq != 0){
    int rbase = (kq-1)*8192 + tile*2048;
    #pragma unroll
    for (int nf = 0; nf < 8; ++nf)
      #pragma unroll
      for (int r = 0; r < 4; ++r)
        sc[rbase + (grp*4 + r)*128 + nf*16 + l15] = acc[nf][r];
  }
  __syncthreads();
  if (kq == 0){
    #pragma unroll
    for (int nf = 0; nf < 8; ++nf)
      #pragma unroll
      for (int r = 0; r < 4; ++r){
        int off = tile*2048 + (grp*4 + r)*128 + nf*16 + l15;
        float hp = acc[nf][r] + sc[off] + sc[8192 + off] + sc[16384 + off];
        float e = hp > 0.f ? hp : __expf(hp) - 1.f;
        size_t o = ((size_t)b*NN + i0 + grp*4 + r)*DD + nf*16 + l15;
        out[o] = e + bf2f(h_lnB[o]);
      }
  }
}

extern "C" void kernel_launch(void* const* d_in, const int* in_sizes, int n_in,
                              void* d_out, int out_size, void* d_ws, size_t ws_size,
                              hipStream_t stream) {
  const float* x     = (const float*)d_in[0];
  const int*   adj   = (const int*)  d_in[1];
  const float* W     = (const float*)d_in[2];
  const float* a1    = (const float*)d_in[3];
  const float* a2    = (const float*)d_in[4];
  const float* nw    = (const float*)d_in[5];
  const float* nb    = (const float*)d_in[6];
  const float* gamma = (const float*)d_in[7];
  const float* beta  = (const float*)d_in[8];
  float* out = (float*)d_out;

  char* ws = (char*)d_ws;
  U16*   h_lnB = (U16*)(ws);                            // 4 MB
  U16*   hTt   = (U16*)(ws + 4*1024*1024);              // 4 MB (tiled)
  float* f1    = (float*)(ws + 8*1024*1024);            // 64 KB
  float* f2    = (float*)(ws + 8*1024*1024 + 64*1024);  // 64 KB
  U16*   WT    = (U16*)(ws + 8*1024*1024 + 128*1024);   // 32 KB
  U32*   adjb  = (U32*)(ws + 9*1024*1024);              // 2 MB

  k0_wt   <<<dim3(64),   dim3(256), 0, stream>>>(W, WT);
  k0b_pack<<<dim3(2048), dim3(256), 0, stream>>>(adj, adjb);
  k1_prep <<<dim3(256),  dim3(256), 0, stream>>>(x, WT, nw, nb, gamma, beta,
                                                 a1, a2, h_lnB, hTt, f1, f2);
  k2_main <<<dim3(256),  dim3(1024), 0, stream>>>(adjb, hTt, f1, f2, h_lnB, out);
}

// Round 7
// 65.703 us; speedup vs baseline: 1.7632x; 1.0156x over previous
//
#include <hip/hip_runtime.h>
#include <hip/hip_bf16.h>

typedef short bfrag8 __attribute__((ext_vector_type(8)));
typedef float f32x4v __attribute__((ext_vector_type(4)));
typedef unsigned short U16;
typedef unsigned int U32;

#define NN 4096
#define DD 128

static __device__ __forceinline__ U16 f2bf(float f){
  union { __hip_bfloat16 b; U16 u; } cv;
  cv.b = __float2bfloat16(f);
  return cv.u;
}

static __device__ __forceinline__ float bf2f(U32 u){
  union { float f; U32 u; } cv;
  cv.u = u << 16;
  return cv.f;
}

// async global->LDS, 16B per lane: lds dest = wave-uniform base + lane*16
#define GLL16(gsrc, ldst) \
  __builtin_amdgcn_global_load_lds((const __attribute__((address_space(1))) unsigned int*)(gsrc), \
                                   (__attribute__((address_space(3))) unsigned int*)(ldst), 16, 0, 0)

// ---------------- kernel 0: adj pack (blocks 0..2047) + W transpose (2048..2111) ----
// adjb[row*128 + g] bit j = adj[row][g*32 + j] != 0 (one u32/thread, own 128B line).
// WT[dp][d] = bf16(W[d][dp]).
__global__ __launch_bounds__(256) void k0_combo(const int* __restrict__ adj,
                                                U32* __restrict__ adjb,
                                                const float* __restrict__ W,
                                                U16* __restrict__ WT){
  if (blockIdx.x >= 2048){
    int i = (blockIdx.x - 2048)*256 + threadIdx.x;  // i = d*128 + dp
    int d = i >> 7, dp = i & 127;
    WT[dp*128 + d] = f2bf(W[i]);
    return;
  }
  int gid = blockIdx.x*256 + threadIdx.x;    // 524288 threads
  const int4* src = reinterpret_cast<const int4*>(adj) + (size_t)gid*8;
  int4 v[8];
  #pragma unroll
  for (int c = 0; c < 8; ++c) v[c] = src[c];
  U32 m = 0;
  #pragma unroll
  for (int c = 0; c < 8; ++c){
    m |= (v[c].x != 0 ? 1u : 0u) << (c*4);
    m |= (v[c].y != 0 ? 2u : 0u) << (c*4);
    m |= (v[c].z != 0 ? 4u : 0u) << (c*4);
    m |= (v[c].w != 0 ? 8u : 0u) << (c*4);
  }
  adjb[gid] = m;
}

// ---------------- kernel 1: x2 = x*(nw+1)+nb; h = LN(x2@W) via MFMA;
// writes h_lnB (bf16 row-major) and hTt (bf16, 32-n tiles, bank-swizzled) -----------
// hTt tile t (= b*128 + n/32), 4096 shorts: addr = D*64 + s*8 + e holds
// h[n = ((s^(D&7))&3)*8 + e][d = 2*D + ((s^(D&7))>>2 & 1)]  (2-way-conflict-free read)
__global__ __launch_bounds__(256) void k1_prep(
    const float* __restrict__ x, const U16* __restrict__ WT,
    const float* __restrict__ nw, const float* __restrict__ nb,
    const float* __restrict__ gamma, const float* __restrict__ beta,
    U16* __restrict__ h_lnB, U16* __restrict__ hTt)
{
  __shared__ U16 lds[16384];                 // 32 KB: WT (swizzled), later hb[64][128]
  const int tid = threadIdx.x;
  const int lane = tid & 63, w = tid >> 6;
  const int l15 = lane & 15, grp = lane >> 4;

  // stage WT into LDS with XOR swizzle (proven R2 pattern)
  #pragma unroll
  for (int q = 0; q < 8; ++q){
    int cid = q*256 + tid;
    int dp = cid >> 4, c = cid & 15;
    *reinterpret_cast<int4*>(lds + dp*128 + ((c*8) ^ ((dp&15)<<3))) =
        *reinterpret_cast<const int4*>(WT + cid*8);
  }
  __syncthreads();

  const int rA = blockIdx.x*64 + w*16 + l15;
  const int nA = rA & 4095;
  const float wgt = nw[nA] + 1.0f, bia = nb[nA];
  const float* xr = x + (size_t)rA*DD;

  f32x4v acc[8] = {};
  #pragma unroll
  for (int ks = 0; ks < 4; ++ks){
    int d8 = ks*32 + grp*8;
    float4 xa = *reinterpret_cast<const float4*>(xr + d8);
    float4 xb = *reinterpret_cast<const float4*>(xr + d8 + 4);
    bfrag8 af;
    af[0] = (short)f2bf(xa.x*wgt + bia);
    af[1] = (short)f2bf(xa.y*wgt + bia);
    af[2] = (short)f2bf(xa.z*wgt + bia);
    af[3] = (short)f2bf(xa.w*wgt + bia);
    af[4] = (short)f2bf(xb.x*wgt + bia);
    af[5] = (short)f2bf(xb.y*wgt + bia);
    af[6] = (short)f2bf(xb.z*wgt + bia);
    af[7] = (short)f2bf(xb.w*wgt + bia);
    #pragma unroll
    for (int nf = 0; nf < 8; ++nf){
      int dp = nf*16 + l15;
      bfrag8 bf = *reinterpret_cast<const bfrag8*>(
          lds + dp*128 + ((((ks*4 + grp)*8)) ^ ((dp&15)<<3)));
      acc[nf] = __builtin_amdgcn_mfma_f32_16x16x32_bf16(af, bf, acc[nf], 0, 0, 0);
    }
  }

  float gc[8], bc[8];
  #pragma unroll
  for (int nf = 0; nf < 8; ++nf){
    int col = nf*16 + l15;
    gc[nf] = gamma[col]; bc[nf] = beta[col];
  }

  // C/D layout: col = lane&15, row = (lane>>4)*4 + r (m89-verified)
  const int rCb = blockIdx.x*64 + w*16 + grp*4;
  #pragma unroll
  for (int r = 0; r < 4; ++r){
    float s = 0.f, qq = 0.f;
    #pragma unroll
    for (int nf = 0; nf < 8; ++nf){ float v = acc[nf][r]; s += v; qq += v*v; }
    #pragma unroll
    for (int m = 1; m < 16; m <<= 1){ s += __shfl_xor(s, m); qq += __shfl_xor(qq, m); }
    float mu = s * 0.0078125f;
    float var = fmaxf(qq*0.0078125f - mu*mu, 0.f);
    float rstd = rsqrtf(var + 1e-5f);
    const int rC = rCb + r;
    #pragma unroll
    for (int nf = 0; nf < 8; ++nf){
      float hn = (acc[nf][r] - mu)*rstd*gc[nf] + bc[nf];
      acc[nf][r] = hn;
      h_lnB[(size_t)rC*DD + nf*16 + l15] = f2bf(hn);
    }
  }

  __syncthreads();   // WT no longer needed; reuse LDS as hb[64 n][128 d]
  #pragma unroll
  for (int r = 0; r < 4; ++r)
    #pragma unroll
    for (int nf = 0; nf < 8; ++nf)
      lds[(w*16 + grp*4 + r)*128 + nf*16 + l15] = f2bf(acc[nf][r]);
  __syncthreads();

  // write 2 hTt tiles (32 rows each), bank-swizzled layout (see header comment)
  {
    const int r0 = blockIdx.x*64;
    const int bB = r0 >> 12;
    const int nbt = (r0 & 4095) >> 5;        // first 32-row tile index
    U16* dstt = hTt + ((size_t)bB*128 + nbt)*4096;
    #pragma unroll
    for (int k = 0; k < 4; ++k){
      int cid = tid*4 + k;                   // 0..1023
      int h2 = cid >> 9;                     // tile half (0,1)
      int D  = (cid >> 3) & 63;
      int sl = cid & 7;
      int t  = sl ^ (D & 7);
      int d  = D*2 + ((t >> 2) & 1);
      int g  = t & 3;
      bfrag8 v;
      #pragma unroll
      for (int e = 0; e < 8; ++e)
        v[e] = (short)lds[(h2*32 + g*8 + e)*128 + d];
      *reinterpret_cast<bfrag8*>(dstt + h2*4096 + D*64 + sl*8) = v;
    }
  }
}

// ---------------- kernel 2: masked-sum GEMM S = (1-adj)@h; out = elu(C*S)+h_ln ----
// grid 256: block = (batch b, 64 i-rows); 8 waves = 2 M-tiles(32 rows) x 4 K-quarters.
// A-fragments generated from adjacency bits (bf16 1.0/0.0). 64 KB LDS -> 2 blocks/CU.
__global__ __launch_bounds__(512, 4) void k2_main(
    const U32* __restrict__ adjb, const U16* __restrict__ hTt,
    const U16* __restrict__ h_lnB, float* __restrict__ out)
{
  __shared__ U16 bt[32768];                  // 64 KB: [buf2][kq4][4096]
  const int tid = threadIdx.x;
  const int lane = tid & 63, w = tid >> 6;
  const int mt = w >> 2, kq = w & 3;
  const int l15 = lane & 15, grp = lane >> 4;
  const int b = blockIdx.x >> 6;
  const int iblk = (blockIdx.x & 63)*64;
  const float CMASK = 0.2f * -9.0e15f;       // leaky(MASK_VAL), exact

  const int row0 = iblk + mt*32 + l15;       // A-frag0 row (lane l15)
  const U32* arow0 = adjb + (size_t)row0*128;
  const U32* arow1 = arow0 + 16*128;         // row0+16

  // staging: tile (kq,s) = hTt[b*128 + kq*32 + s]; wave stages its mt-half (4 KB)
  const U16* sbase = hTt + ((size_t)b*128 + kq*32)*4096 + mt*2048 + lane*8;
  const int dbase = kq*4096 + mt*2048;

  // prologue: stage s=0 into buf 0
  #pragma unroll
  for (int c = 0; c < 4; ++c)
    GLL16(sbase + c*512, &bt[dbase + c*512]);
  U32 cw0 = arow0[kq*32], cw1 = arow1[kq*32];

  f32x4v acc0[8] = {}, acc1[8] = {};
  __syncthreads();                            // tile 0 staged

  for (int s = 0; s < 32; ++s){
    if (s < 31){                              // issue next tile's staging first
      const U16* gp = sbase + (size_t)(s+1)*4096;
      int dsto = ((s+1)&1)*16384 + dbase;
      #pragma unroll
      for (int c = 0; c < 4; ++c)
        GLL16(gp + c*512, &bt[dsto + c*512]);
    }
    U32 nw0, nw1;
    if (s < 31){ nw0 = arow0[kq*32 + s+1]; nw1 = arow1[kq*32 + s+1]; }

    // A-fragments from inverted adjacency bits: bit=0 -> 1.0, bit=1 -> 0
    const U32 b0 = (cw0 >> (grp*8)) & 0xffu;
    const U32 b1 = (cw1 >> (grp*8)) & 0xffu;
    bfrag8 af0, af1;
    #pragma unroll
    for (int e = 0; e < 8; ++e){
      af0[e] = (b0 & (1u<<e)) ? (short)0 : (short)0x3F80;
      af1[e] = (b1 & (1u<<e)) ? (short)0 : (short)0x3F80;
    }

    const int base = (s&1)*16384 + kq*4096;
    #pragma unroll
    for (int nf = 0; nf < 8; ++nf){
      int d = nf*16 + l15;
      int D = d >> 1;
      int sl = (((d&1)<<2) | grp) ^ (D&7);
      bfrag8 bf = *reinterpret_cast<const bfrag8*>(bt + base + D*64 + sl*8);
      acc0[nf] = __builtin_amdgcn_mfma_f32_16x16x32_bf16(af0, bf, acc0[nf], 0, 0, 0);
      acc1[nf] = __builtin_amdgcn_mfma_f32_16x16x32_bf16(af1, bf, acc1[nf], 0, 0, 0);
    }

    __syncthreads();   // all waves done with buf[s&1]; next staging drained here
    cw0 = nw0; cw1 = nw1;
  }

  // ---- K-quarter combine via bf16 scratch (48 KB in bt), then fused epilogue ----
  // region (kq-1, mt): base = ((kq-1)*2+mt)*4096 shorts; col-major:
  // addr = col*32 + ((f*16 + grp*4) ^ ((col&7)<<2)) + rpair*2   (XOR de-conflict)
  __syncthreads();
  if (kq != 0){
    const int rb = ((kq-1)*2 + mt)*4096;
    #pragma unroll
    for (int f = 0; f < 2; ++f){
      #pragma unroll
      for (int nf = 0; nf < 8; ++nf){
        const f32x4v a = f ? acc1[nf] : acc0[nf];
        const int col = nf*16 + l15;
        const int ro = (f*16 + grp*4) ^ ((col&7)<<2);
        U32 p0 = (U32)f2bf(a[0]) | ((U32)f2bf(a[1]) << 16);
        U32 p1 = (U32)f2bf(a[2]) | ((U32)f2bf(a[3]) << 16);
        *reinterpret_cast<U32*>(bt + rb + col*32 + ro)     = p0;
        *reinterpret_cast<U32*>(bt + rb + col*32 + ro + 2) = p1;
      }
    }
  }
  __syncthreads();
  if (kq == 0){
    #pragma unroll
    for (int f = 0; f < 2; ++f){
      #pragma unroll
      for (int nf = 0; nf < 8; ++nf){
        const f32x4v a = f ? acc1[nf] : acc0[nf];
        const int col = nf*16 + l15;
        const int ro = (f*16 + grp*4) ^ ((col&7)<<2);
        float s0 = a[0], s1 = a[1], s2 = a[2], s3 = a[3];
        #pragma unroll
        for (int reg = 0; reg < 3; ++reg){
          const int rb = (reg*2 + mt)*4096;
          U32 p0 = *reinterpret_cast<const U32*>(bt + rb + col*32 + ro);
          U32 p1 = *reinterpret_cast<const U32*>(bt + rb + col*32 + ro + 2);
          s0 += bf2f(p0 & 0xffffu); s1 += bf2f(p0 >> 16);
          s2 += bf2f(p1 & 0xffffu); s3 += bf2f(p1 >> 16);
        }
        float sv[4] = {s0, s1, s2, s3};
        #pragma unroll
        for (int r = 0; r < 4; ++r){
          float hp = CMASK * sv[r];
          float e = hp > 0.f ? hp : __expf(hp) - 1.f;
          const int rowb = iblk + mt*32 + f*16 + grp*4 + r;
          const size_t o = ((size_t)b*NN + rowb)*DD + col;
          out[o] = e + bf2f((U32)h_lnB[o]);
        }
      }
    }
  }
}

extern "C" void kernel_launch(void* const* d_in, const int* in_sizes, int n_in,
                              void* d_out, int out_size, void* d_ws, size_t ws_size,
                              hipStream_t stream) {
  const float* x     = (const float*)d_in[0];
  const int*   adj   = (const int*)  d_in[1];
  const float* W     = (const float*)d_in[2];
  const float* nw    = (const float*)d_in[5];
  const float* nb    = (const float*)d_in[6];
  const float* gamma = (const float*)d_in[7];
  const float* beta  = (const float*)d_in[8];
  float* out = (float*)d_out;

  char* ws = (char*)d_ws;
  U16*   h_lnB = (U16*)(ws);                            // 4 MB
  U16*   hTt   = (U16*)(ws + 4*1024*1024);              // 4 MB (tiled)
  U16*   WT    = (U16*)(ws + 8*1024*1024);              // 32 KB
  U32*   adjb  = (U32*)(ws + 9*1024*1024);              // 2 MB

  k0_combo<<<dim3(2112), dim3(256), 0, stream>>>(adj, adjb, W, WT);
  k1_prep <<<dim3(256),  dim3(256), 0, stream>>>(x, WT, nw, nb, gamma, beta,
                                                 h_lnB, hTt);
  k2_main <<<dim3(256),  dim3(512), 0, stream>>>(adjb, hTt, h_lnB, out);
}

// Round 8
// 52.617 us; speedup vs baseline: 2.2017x; 1.2487x over previous
//
#include <hip/hip_runtime.h>
#include <hip/hip_bf16.h>

typedef short bfrag8 __attribute__((ext_vector_type(8)));
typedef float f32x4v __attribute__((ext_vector_type(4)));
typedef unsigned short U16;
typedef unsigned int U32;

#define NN 4096
#define DD 128

static __device__ __forceinline__ U16 f2bf(float f){
  union { __hip_bfloat16 b; U16 u; } cv;
  cv.b = __float2bfloat16(f);
  return cv.u;
}

static __device__ __forceinline__ float bf2f(U32 u){
  union { float f; U32 u; } cv;
  cv.u = u << 16;
  return cv.f;
}

// A-fragment from inverted adjacency bits: bit=0 -> 1.0bf16, bit=1 -> 0
static __device__ __forceinline__ bfrag8 afrag(U32 word, int grp){
  U32 y = (word >> (grp*8)) & 0xffu;
  bfrag8 a;
  #pragma unroll
  for (int e = 0; e < 8; ++e) a[e] = (y & (1u<<e)) ? (short)0 : (short)0x3F80;
  return a;
}

// ---------------- kernel 0: adj pack (blocks 0..2047) + W transpose (2048..2111) ----
__global__ __launch_bounds__(256) void k0_combo(const int* __restrict__ adj,
                                                U32* __restrict__ adjb,
                                                const float* __restrict__ W,
                                                U16* __restrict__ WT){
  if (blockIdx.x >= 2048){
    int i = (blockIdx.x - 2048)*256 + threadIdx.x;  // i = d*128 + dp
    int d = i >> 7, dp = i & 127;
    WT[dp*128 + d] = f2bf(W[i]);
    return;
  }
  int gid = blockIdx.x*256 + threadIdx.x;    // 524288 threads
  const int4* src = reinterpret_cast<const int4*>(adj) + (size_t)gid*8;
  int4 v[8];
  #pragma unroll
  for (int c = 0; c < 8; ++c) v[c] = src[c];
  U32 m = 0;
  #pragma unroll
  for (int c = 0; c < 8; ++c){
    m |= (v[c].x != 0 ? 1u : 0u) << (c*4);
    m |= (v[c].y != 0 ? 2u : 0u) << (c*4);
    m |= (v[c].z != 0 ? 4u : 0u) << (c*4);
    m |= (v[c].w != 0 ? 8u : 0u) << (c*4);
  }
  adjb[gid] = m;
}

// ---------------- kernel 1: x2 = x*(nw+1)+nb; h = LN(x2@W) via MFMA;
// writes h_lnB (bf16 row-major) and hTt: element (b,n,d) at
// ((b*128 + n/32)*128 + d)*32 + (n&31) shorts  -> a wave's 8 B-fragment loads
// for one (tile, k-window) are 1KB fully contiguous (direct-to-register GEMM).
__global__ __launch_bounds__(256) void k1_prep(
    const float* __restrict__ x, const U16* __restrict__ WT,
    const float* __restrict__ nw, const float* __restrict__ nb,
    const float* __restrict__ gamma, const float* __restrict__ beta,
    U16* __restrict__ h_lnB, U16* __restrict__ hTt)
{
  __shared__ U16 lds[16384];                 // 32 KB: WT (swizzled), later hb[64][128]
  const int tid = threadIdx.x;
  const int lane = tid & 63, w = tid >> 6;
  const int l15 = lane & 15, grp = lane >> 4;

  // stage WT into LDS with XOR swizzle (proven R2 pattern)
  #pragma unroll
  for (int q = 0; q < 8; ++q){
    int cid = q*256 + tid;
    int dp = cid >> 4, c = cid & 15;
    *reinterpret_cast<int4*>(lds + dp*128 + ((c*8) ^ ((dp&15)<<3))) =
        *reinterpret_cast<const int4*>(WT + cid*8);
  }
  __syncthreads();

  const int rA = blockIdx.x*64 + w*16 + l15;
  const int nA = rA & 4095;
  const float wgt = nw[nA] + 1.0f, bia = nb[nA];
  const float* xr = x + (size_t)rA*DD;

  f32x4v acc[8] = {};
  #pragma unroll
  for (int ks = 0; ks < 4; ++ks){
    int d8 = ks*32 + grp*8;
    float4 xa = *reinterpret_cast<const float4*>(xr + d8);
    float4 xb = *reinterpret_cast<const float4*>(xr + d8 + 4);
    bfrag8 af;
    af[0] = (short)f2bf(xa.x*wgt + bia);
    af[1] = (short)f2bf(xa.y*wgt + bia);
    af[2] = (short)f2bf(xa.z*wgt + bia);
    af[3] = (short)f2bf(xa.w*wgt + bia);
    af[4] = (short)f2bf(xb.x*wgt + bia);
    af[5] = (short)f2bf(xb.y*wgt + bia);
    af[6] = (short)f2bf(xb.z*wgt + bia);
    af[7] = (short)f2bf(xb.w*wgt + bia);
    #pragma unroll
    for (int nf = 0; nf < 8; ++nf){
      int dp = nf*16 + l15;
      bfrag8 bf = *reinterpret_cast<const bfrag8*>(
          lds + dp*128 + ((((ks*4 + grp)*8)) ^ ((dp&15)<<3)));
      acc[nf] = __builtin_amdgcn_mfma_f32_16x16x32_bf16(af, bf, acc[nf], 0, 0, 0);
    }
  }

  float gc[8], bc[8];
  #pragma unroll
  for (int nf = 0; nf < 8; ++nf){
    int col = nf*16 + l15;
    gc[nf] = gamma[col]; bc[nf] = beta[col];
  }

  // C/D layout: col = lane&15, row = (lane>>4)*4 + r (m89-verified)
  const int rCb = blockIdx.x*64 + w*16 + grp*4;
  #pragma unroll
  for (int r = 0; r < 4; ++r){
    float s = 0.f, qq = 0.f;
    #pragma unroll
    for (int nf = 0; nf < 8; ++nf){ float v = acc[nf][r]; s += v; qq += v*v; }
    #pragma unroll
    for (int m = 1; m < 16; m <<= 1){ s += __shfl_xor(s, m); qq += __shfl_xor(qq, m); }
    float mu = s * 0.0078125f;
    float var = fmaxf(qq*0.0078125f - mu*mu, 0.f);
    float rstd = rsqrtf(var + 1e-5f);
    const int rC = rCb + r;
    #pragma unroll
    for (int nf = 0; nf < 8; ++nf){
      float hn = (acc[nf][r] - mu)*rstd*gc[nf] + bc[nf];
      acc[nf][r] = hn;
      h_lnB[(size_t)rC*DD + nf*16 + l15] = f2bf(hn);
    }
  }

  __syncthreads();   // WT no longer needed; reuse LDS as hb[64 n][128 d]
  #pragma unroll
  for (int r = 0; r < 4; ++r)
    #pragma unroll
    for (int nf = 0; nf < 8; ++nf)
      lds[(w*16 + grp*4 + r)*128 + nf*16 + l15] = f2bf(acc[nf][r]);
  __syncthreads();

  // write 2 hTt tiles (32 n each): thread tid -> (h2 = tid>>7, d = tid&127),
  // 4 chunks g: dest ((bB*128+nt0+h2)*128 + d)*32 + g*8 (coalesced 64B/thread)
  {
    const int r0 = blockIdx.x*64;
    const int bB = r0 >> 12;
    const int nt0 = (r0 & 4095) >> 5;
    U16* dstt = hTt + ((size_t)(bB*128 + nt0)*128)*32;
    const int h2 = tid >> 7, d = tid & 127;
    #pragma unroll
    for (int g = 0; g < 4; ++g){
      bfrag8 v;
      #pragma unroll
      for (int e = 0; e < 8; ++e)
        v[e] = (short)lds[(h2*32 + g*8 + e)*128 + d];
      *reinterpret_cast<bfrag8*>(dstt + ((size_t)(h2*128 + d))*32 + g*8) = v;
    }
  }
}

// ---------------- kernel 2: S = (1-adj)@h direct-to-register GEMM ----------------
// grid 256: block = (batch b, 64 i-rows); 8 waves, wave w = K-eighth (512 K).
// No LDS, no barriers in main loop: B-frags global->reg double-banked, adj bits
// prefetched; compiler emits counted vmcnt. One barrier for the K-combine.
__global__ __launch_bounds__(512, 2) void k2_main(
    const U32* __restrict__ adjb, const U16* __restrict__ hTt,
    const U16* __restrict__ h_lnB, float* __restrict__ out)
{
  __shared__ U16 part[65536];                // 128 KB: 8 regions x [64 r][128 c] bf16
  const int tid = threadIdx.x;
  const int lane = tid & 63, w = tid >> 6;   // w = K-eighth
  const int l15 = lane & 15, grp = lane >> 4;
  const int b = blockIdx.x >> 6;
  const int iblk = (blockIdx.x & 63) * 64;
  const float CMASK = 0.2f * -9.0e15f;       // leaky(MASK_VAL), exact

  const U32* ar0 = adjb + (size_t)(iblk +      l15)*128 + w*16;
  const U32* ar1 = adjb + (size_t)(iblk + 16 + l15)*128 + w*16;
  const U32* ar2 = adjb + (size_t)(iblk + 32 + l15)*128 + w*16;
  const U32* ar3 = adjb + (size_t)(iblk + 48 + l15)*128 + w*16;

  // B-fragment base: tile (b*128 + w*16 + s), lane offset l15*32 + grp*8 shorts;
  // nf stride 512 shorts; s stride 4096 shorts. Wave's 8 loads/step = 1KB contig.
  const U16* bp = hTt + ((size_t)(b*128 + w*16)*128)*32 + l15*32 + grp*8;

  f32x4v acc[4][8] = {};

#define LOADB(P0,P1,P2,P3,P4,P5,P6,P7, S) do { \
    const U16* _q = bp + (size_t)(S)*4096; \
    P0 = *reinterpret_cast<const bfrag8*>(_q);        \
    P1 = *reinterpret_cast<const bfrag8*>(_q + 512);  \
    P2 = *reinterpret_cast<const bfrag8*>(_q + 1024); \
    P3 = *reinterpret_cast<const bfrag8*>(_q + 1536); \
    P4 = *reinterpret_cast<const bfrag8*>(_q + 2048); \
    P5 = *reinterpret_cast<const bfrag8*>(_q + 2560); \
    P6 = *reinterpret_cast<const bfrag8*>(_q + 3072); \
    P7 = *reinterpret_cast<const bfrag8*>(_q + 3584); } while(0)

#define COLM(CF, NF) do { \
    acc[0][NF] = __builtin_amdgcn_mfma_f32_16x16x32_bf16(a0, CF, acc[0][NF], 0,0,0); \
    acc[1][NF] = __builtin_amdgcn_mfma_f32_16x16x32_bf16(a1, CF, acc[1][NF], 0,0,0); \
    acc[2][NF] = __builtin_amdgcn_mfma_f32_16x16x32_bf16(a2, CF, acc[2][NF], 0,0,0); \
    acc[3][NF] = __builtin_amdgcn_mfma_f32_16x16x32_bf16(a3, CF, acc[3][NF], 0,0,0); } while(0)

#define COMPUTE(P0,P1,P2,P3,P4,P5,P6,P7, W0,W1,W2,W3) do { \
    bfrag8 a0 = afrag(W0, grp), a1 = afrag(W1, grp); \
    bfrag8 a2 = afrag(W2, grp), a3 = afrag(W3, grp); \
    COLM(P0, 0); COLM(P1, 1); COLM(P2, 2); COLM(P3, 3); \
    COLM(P4, 4); COLM(P5, 5); COLM(P6, 6); COLM(P7, 7); } while(0)

  bfrag8 A0,A1,A2,A3,A4,A5,A6,A7, B0,B1,B2,B3,B4,B5,B6,B7;
  U32 wa0,wa1,wa2,wa3, wb0,wb1,wb2,wb3;

  LOADB(A0,A1,A2,A3,A4,A5,A6,A7, 0);
  wa0 = ar0[0]; wa1 = ar1[0]; wa2 = ar2[0]; wa3 = ar3[0];

  #pragma unroll 1
  for (int it = 0; it < 8; ++it){
    const int s = it*2;
    LOADB(B0,B1,B2,B3,B4,B5,B6,B7, s+1);
    wb0 = ar0[s+1]; wb1 = ar1[s+1]; wb2 = ar2[s+1]; wb3 = ar3[s+1];
    COMPUTE(A0,A1,A2,A3,A4,A5,A6,A7, wa0,wa1,wa2,wa3);
    LOADB(A0,A1,A2,A3,A4,A5,A6,A7, s+2);     // s+2==16 on last iter: reads pad
    wa0 = ar0[s+2]; wa1 = ar1[s+2]; wa2 = ar2[s+2]; wa3 = ar3[s+2];
    COMPUTE(B0,B1,B2,B3,B4,B5,B6,B7, wb0,wb1,wb2,wb3);
  }

  // ---- K-combine: bf16 partials in LDS, XOR-swizzled (2 lanes/bank = free) ----
  U16* reg = part + w*8192;
  #pragma unroll
  for (int f = 0; f < 4; ++f)
    #pragma unroll
    for (int nf = 0; nf < 8; ++nf){
      const int col = nf*16 + l15;
      #pragma unroll
      for (int r = 0; r < 4; ++r){
        const int lr = f*16 + grp*4 + r;
        reg[lr*128 + (col ^ (((lr>>2)&3)<<4))] = f2bf(acc[f][nf][r]);
      }
    }
  __syncthreads();

  #pragma unroll
  for (int rr = 0; rr < 8; ++rr){
    const int row = w*8 + rr;
    const int ci = row*64 + (lane ^ (((row>>2)&3)<<3));   // u32 index (row-const XOR)
    float s0 = 0.f, s1 = 0.f;
    #pragma unroll
    for (int q = 0; q < 8; ++q){
      U32 p = reinterpret_cast<const U32*>(part)[q*4096 + ci];
      s0 += bf2f(p & 0xffffu); s1 += bf2f(p >> 16);
    }
    const float h0 = CMASK * s0, h1 = CMASK * s1;
    const float e0 = h0 > 0.f ? h0 : __expf(h0) - 1.f;
    const float e1 = h1 > 0.f ? h1 : __expf(h1) - 1.f;
    const size_t o = ((size_t)b*NN + iblk + row)*DD + 2*lane;
    const U32 hl = *reinterpret_cast<const U32*>(h_lnB + o);
    float2 ov; ov.x = e0 + bf2f(hl & 0xffffu); ov.y = e1 + bf2f(hl >> 16);
    *reinterpret_cast<float2*>(out + o) = ov;
  }
}

extern "C" void kernel_launch(void* const* d_in, const int* in_sizes, int n_in,
                              void* d_out, int out_size, void* d_ws, size_t ws_size,
                              hipStream_t stream) {
  const float* x     = (const float*)d_in[0];
  const int*   adj   = (const int*)  d_in[1];
  const float* W     = (const float*)d_in[2];
  const float* nw    = (const float*)d_in[5];
  const float* nb    = (const float*)d_in[6];
  const float* gamma = (const float*)d_in[7];
  const float* beta  = (const float*)d_in[8];
  float* out = (float*)d_out;

  char* ws = (char*)d_ws;
  U16*   h_lnB = (U16*)(ws);                            // 4 MB
  U16*   hTt   = (U16*)(ws + 4*1024*1024);              // 4 MB + 16 KB pad
  U16*   WT    = (U16*)(ws + 8*1024*1024 + 16*1024);    // 32 KB
  U32*   adjb  = (U32*)(ws + 9*1024*1024);              // 2 MB + 4 KB pad

  k0_combo<<<dim3(2112), dim3(256), 0, stream>>>(adj, adjb, W, WT);
  k1_prep <<<dim3(256),  dim3(256), 0, stream>>>(x, WT, nw, nb, gamma, beta,
                                                 h_lnB, hTt);
  k2_main <<<dim3(256),  dim3(512), 0, stream>>>(adjb, hTt, h_lnB, out);
}

// Round 9
// 51.735 us; speedup vs baseline: 2.2392x; 1.0170x over previous
//
#include <hip/hip_runtime.h>
#include <hip/hip_bf16.h>

typedef short bfrag8 __attribute__((ext_vector_type(8)));
typedef float f32x4v __attribute__((ext_vector_type(4)));
typedef unsigned short U16;
typedef unsigned int U32;

#define NN 4096
#define DD 128

static __device__ __forceinline__ U16 f2bf(float f){
  union { __hip_bfloat16 b; U16 u; } cv;
  cv.b = __float2bfloat16(f);
  return cv.u;
}

static __device__ __forceinline__ float bf2f(U32 u){
  union { float f; U32 u; } cv;
  cv.u = u << 16;
  return cv.f;
}

// A-fragment from inverted adjacency bits: bit=0 -> 1.0bf16, bit=1 -> 0
static __device__ __forceinline__ bfrag8 afrag(U32 word, int grp){
  U32 y = (word >> (grp*8)) & 0xffu;
  bfrag8 a;
  #pragma unroll
  for (int e = 0; e < 8; ++e) a[e] = (y & (1u<<e)) ? (short)0 : (short)0x3F80;
  return a;
}

// ---------------- kernel 0: adj pack TRANSPOSED (blocks 0..2047) + W^T (2048..2111) --
// adjbT[g*4096 + row] bit j = adj[row][g*32 + j] != 0  (g = 32-col group).
// thread = (g, row): reads its own 128B of adj row (fully consumed), writes coalesced.
__global__ __launch_bounds__(256) void k0_combo(const int* __restrict__ adj,
                                                U32* __restrict__ adjbT,
                                                const float* __restrict__ W,
                                                U16* __restrict__ WT){
  if (blockIdx.x >= 2048){
    int i = (blockIdx.x - 2048)*256 + threadIdx.x;  // i = d*128 + dp
    int d = i >> 7, dp = i & 127;
    WT[dp*128 + d] = f2bf(W[i]);
    return;
  }
  const int g   = blockIdx.x >> 4;                  // 0..127
  const int row = (blockIdx.x & 15)*256 + threadIdx.x;
  const int4* src = reinterpret_cast<const int4*>(adj + (size_t)row*NN + g*32);
  int4 v[8];
  #pragma unroll
  for (int c = 0; c < 8; ++c) v[c] = src[c];
  U32 m = 0;
  #pragma unroll
  for (int c = 0; c < 8; ++c){
    m |= (v[c].x != 0 ? 1u : 0u) << (c*4);
    m |= (v[c].y != 0 ? 2u : 0u) << (c*4);
    m |= (v[c].z != 0 ? 4u : 0u) << (c*4);
    m |= (v[c].w != 0 ? 8u : 0u) << (c*4);
  }
  adjbT[(size_t)g*4096 + row] = m;
}

// ---------------- kernel 1: x2 = x*(nw+1)+nb; h = LN(x2@W) via MFMA;
// writes h_lnB (bf16 row-major) and hTt: element (b,n,d) at
// ((b*128 + n/32)*128 + d)*32 + (n&31) shorts  -> a wave's 8 B-fragment loads
// for one (tile, k-window) are 1KB fully contiguous (direct-to-register GEMM).
__global__ __launch_bounds__(256) void k1_prep(
    const float* __restrict__ x, const U16* __restrict__ WT,
    const float* __restrict__ nw, const float* __restrict__ nb,
    const float* __restrict__ gamma, const float* __restrict__ beta,
    U16* __restrict__ h_lnB, U16* __restrict__ hTt)
{
  __shared__ U16 lds[16384];                 // 32 KB: WT (swizzled), later hb[64][128]
  const int tid = threadIdx.x;
  const int lane = tid & 63, w = tid >> 6;
  const int l15 = lane & 15, grp = lane >> 4;

  // stage WT into LDS with XOR swizzle (proven R2 pattern)
  #pragma unroll
  for (int q = 0; q < 8; ++q){
    int cid = q*256 + tid;
    int dp = cid >> 4, c = cid & 15;
    *reinterpret_cast<int4*>(lds + dp*128 + ((c*8) ^ ((dp&15)<<3))) =
        *reinterpret_cast<const int4*>(WT + cid*8);
  }
  __syncthreads();

  const int rA = blockIdx.x*64 + w*16 + l15;
  const int nA = rA & 4095;
  const float wgt = nw[nA] + 1.0f, bia = nb[nA];
  const float* xr = x + (size_t)rA*DD;

  f32x4v acc[8] = {};
  #pragma unroll
  for (int ks = 0; ks < 4; ++ks){
    int d8 = ks*32 + grp*8;
    float4 xa = *reinterpret_cast<const float4*>(xr + d8);
    float4 xb = *reinterpret_cast<const float4*>(xr + d8 + 4);
    bfrag8 af;
    af[0] = (short)f2bf(xa.x*wgt + bia);
    af[1] = (short)f2bf(xa.y*wgt + bia);
    af[2] = (short)f2bf(xa.z*wgt + bia);
    af[3] = (short)f2bf(xa.w*wgt + bia);
    af[4] = (short)f2bf(xb.x*wgt + bia);
    af[5] = (short)f2bf(xb.y*wgt + bia);
    af[6] = (short)f2bf(xb.z*wgt + bia);
    af[7] = (short)f2bf(xb.w*wgt + bia);
    #pragma unroll
    for (int nf = 0; nf < 8; ++nf){
      int dp = nf*16 + l15;
      bfrag8 bf = *reinterpret_cast<const bfrag8*>(
          lds + dp*128 + ((((ks*4 + grp)*8)) ^ ((dp&15)<<3)));
      acc[nf] = __builtin_amdgcn_mfma_f32_16x16x32_bf16(af, bf, acc[nf], 0, 0, 0);
    }
  }

  float gc[8], bc[8];
  #pragma unroll
  for (int nf = 0; nf < 8; ++nf){
    int col = nf*16 + l15;
    gc[nf] = gamma[col]; bc[nf] = beta[col];
  }

  // C/D layout: col = lane&15, row = (lane>>4)*4 + r (m89-verified)
  const int rCb = blockIdx.x*64 + w*16 + grp*4;
  #pragma unroll
  for (int r = 0; r < 4; ++r){
    float s = 0.f, qq = 0.f;
    #pragma unroll
    for (int nf = 0; nf < 8; ++nf){ float v = acc[nf][r]; s += v; qq += v*v; }
    #pragma unroll
    for (int m = 1; m < 16; m <<= 1){ s += __shfl_xor(s, m); qq += __shfl_xor(qq, m); }
    float mu = s * 0.0078125f;
    float var = fmaxf(qq*0.0078125f - mu*mu, 0.f);
    float rstd = rsqrtf(var + 1e-5f);
    const int rC = rCb + r;
    #pragma unroll
    for (int nf = 0; nf < 8; ++nf){
      float hn = (acc[nf][r] - mu)*rstd*gc[nf] + bc[nf];
      acc[nf][r] = hn;
      h_lnB[(size_t)rC*DD + nf*16 + l15] = f2bf(hn);
    }
  }

  __syncthreads();   // WT no longer needed; reuse LDS as hb[64 n][128 d]
  #pragma unroll
  for (int r = 0; r < 4; ++r)
    #pragma unroll
    for (int nf = 0; nf < 8; ++nf)
      lds[(w*16 + grp*4 + r)*128 + nf*16 + l15] = f2bf(acc[nf][r]);
  __syncthreads();

  // write 2 hTt tiles (32 n each): thread tid -> (h2 = tid>>7, d = tid&127),
  // 4 chunks g: dest ((bB*128+nt0+h2)*128 + d)*32 + g*8 (coalesced 64B/thread)
  {
    const int r0 = blockIdx.x*64;
    const int bB = r0 >> 12;
    const int nt0 = (r0 & 4095) >> 5;
    U16* dstt = hTt + ((size_t)(bB*128 + nt0)*128)*32;
    const int h2 = tid >> 7, d = tid & 127;
    #pragma unroll
    for (int g = 0; g < 4; ++g){
      bfrag8 v;
      #pragma unroll
      for (int e = 0; e < 8; ++e)
        v[e] = (short)lds[(h2*32 + g*8 + e)*128 + d];
      *reinterpret_cast<bfrag8*>(dstt + ((size_t)(h2*128 + d))*32 + g*8) = v;
    }
  }
}

// ---------------- kernel 2: S = (1-adj)@h direct-to-register GEMM ----------------
// XCD-aware mapping: xcd = bid&7 owns batch b = xcd>>1 -> hTt[b] (1MB) + adjbT
// slice (1MB) stay resident in that XCD's 4MB L2. 8 waves, wave = K-eighth.
// No barriers in main loop; B-frags global->reg double-banked (counted vmcnt).
__global__ __launch_bounds__(512, 2) void k2_main(
    const U32* __restrict__ adjbT, const U16* __restrict__ hTt,
    const U16* __restrict__ h_lnB, float* __restrict__ out)
{
  __shared__ U16 part[65536];                // 128 KB: 8 regions x [64 r][128 c] bf16
  const int tid = threadIdx.x;
  const int lane = tid & 63, w = tid >> 6;   // w = K-eighth
  const int l15 = lane & 15, grp = lane >> 4;
  const int bid = blockIdx.x;
  const int xcd = bid & 7;
  const int b = xcd >> 1;                    // batch pinned to XCD pair
  const int iblk = ((((bid >> 3) << 1) | (xcd & 1))) * 64;
  const float CMASK = 0.2f * -9.0e15f;       // leaky(MASK_VAL), exact

  // transposed adj bits: word (g = w*16+s) for row f*16+l15 -> 16 consecutive u32
  const U32* ar0 = adjbT + (size_t)(w*16)*4096 + iblk +      l15;
  const U32* ar1 = adjbT + (size_t)(w*16)*4096 + iblk + 16 + l15;
  const U32* ar2 = adjbT + (size_t)(w*16)*4096 + iblk + 32 + l15;
  const U32* ar3 = adjbT + (size_t)(w*16)*4096 + iblk + 48 + l15;

  // B-fragment base: tile (b*128 + w*16 + s), lane offset l15*32 + grp*8 shorts;
  // nf stride 512 shorts; s stride 4096 shorts. Wave's 8 loads/step = 1KB contig.
  const U16* bp = hTt + ((size_t)(b*128 + w*16)*128)*32 + l15*32 + grp*8;

  f32x4v acc[4][8] = {};

#define LOADB(P0,P1,P2,P3,P4,P5,P6,P7, S) do { \
    const U16* _q = bp + (size_t)(S)*4096; \
    P0 = *reinterpret_cast<const bfrag8*>(_q);        \
    P1 = *reinterpret_cast<const bfrag8*>(_q + 512);  \
    P2 = *reinterpret_cast<const bfrag8*>(_q + 1024); \
    P3 = *reinterpret_cast<const bfrag8*>(_q + 1536); \
    P4 = *reinterpret_cast<const bfrag8*>(_q + 2048); \
    P5 = *reinterpret_cast<const bfrag8*>(_q + 2560); \
    P6 = *reinterpret_cast<const bfrag8*>(_q + 3072); \
    P7 = *reinterpret_cast<const bfrag8*>(_q + 3584); } while(0)

#define COLM(CF, NF) do { \
    acc[0][NF] = __builtin_amdgcn_mfma_f32_16x16x32_bf16(a0, CF, acc[0][NF], 0,0,0); \
    acc[1][NF] = __builtin_amdgcn_mfma_f32_16x16x32_bf16(a1, CF, acc[1][NF], 0,0,0); \
    acc[2][NF] = __builtin_amdgcn_mfma_f32_16x16x32_bf16(a2, CF, acc[2][NF], 0,0,0); \
    acc[3][NF] = __builtin_amdgcn_mfma_f32_16x16x32_bf16(a3, CF, acc[3][NF], 0,0,0); } while(0)

#define COMPUTE(P0,P1,P2,P3,P4,P5,P6,P7, W0,W1,W2,W3) do { \
    bfrag8 a0 = afrag(W0, grp), a1 = afrag(W1, grp); \
    bfrag8 a2 = afrag(W2, grp), a3 = afrag(W3, grp); \
    COLM(P0, 0); COLM(P1, 1); COLM(P2, 2); COLM(P3, 3); \
    COLM(P4, 4); COLM(P5, 5); COLM(P6, 6); COLM(P7, 7); } while(0)

  bfrag8 A0,A1,A2,A3,A4,A5,A6,A7, B0,B1,B2,B3,B4,B5,B6,B7;
  U32 wa0,wa1,wa2,wa3, wb0,wb1,wb2,wb3;

  LOADB(A0,A1,A2,A3,A4,A5,A6,A7, 0);
  wa0 = ar0[0]; wa1 = ar1[0]; wa2 = ar2[0]; wa3 = ar3[0];

  #pragma unroll 1
  for (int it = 0; it < 8; ++it){
    const int s = it*2;
    LOADB(B0,B1,B2,B3,B4,B5,B6,B7, s+1);
    wb0 = ar0[(s+1)*4096]; wb1 = ar1[(s+1)*4096];
    wb2 = ar2[(s+1)*4096]; wb3 = ar3[(s+1)*4096];
    COMPUTE(A0,A1,A2,A3,A4,A5,A6,A7, wa0,wa1,wa2,wa3);
    LOADB(A0,A1,A2,A3,A4,A5,A6,A7, s+2);     // s+2==16 on last iter: reads pad
    wa0 = ar0[(s+2)*4096]; wa1 = ar1[(s+2)*4096];
    wa2 = ar2[(s+2)*4096]; wa3 = ar3[(s+2)*4096];
    COMPUTE(B0,B1,B2,B3,B4,B5,B6,B7, wb0,wb1,wb2,wb3);
  }

  // ---- K-combine: bf16 partials in LDS, XOR-swizzled (2 lanes/bank = free) ----
  U16* reg = part + w*8192;
  #pragma unroll
  for (int f = 0; f < 4; ++f)
    #pragma unroll
    for (int nf = 0; nf < 8; ++nf){
      const int col = nf*16 + l15;
      #pragma unroll
      for (int r = 0; r < 4; ++r){
        const int lr = f*16 + grp*4 + r;
        reg[lr*128 + (col ^ (((lr>>2)&3)<<4))] = f2bf(acc[f][nf][r]);
      }
    }
  __syncthreads();

  #pragma unroll
  for (int rr = 0; rr < 8; ++rr){
    const int row = w*8 + rr;
    const int ci = row*64 + (lane ^ (((row>>2)&3)<<3));   // u32 index (row-const XOR)
    float s0 = 0.f, s1 = 0.f;
    #pragma unroll
    for (int q = 0; q < 8; ++q){
      U32 p = reinterpret_cast<const U32*>(part)[q*4096 + ci];
      s0 += bf2f(p & 0xffffu); s1 += bf2f(p >> 16);
    }
    const float h0 = CMASK * s0, h1 = CMASK * s1;
    const float e0 = h0 > 0.f ? h0 : __expf(h0) - 1.f;
    const float e1 = h1 > 0.f ? h1 : __expf(h1) - 1.f;
    const size_t o = ((size_t)b*NN + iblk + row)*DD + 2*lane;
    const U32 hl = *reinterpret_cast<const U32*>(h_lnB + o);
    float2 ov; ov.x = e0 + bf2f(hl & 0xffffu); ov.y = e1 + bf2f(hl >> 16);
    *reinterpret_cast<float2*>(out + o) = ov;
  }
}

extern "C" void kernel_launch(void* const* d_in, const int* in_sizes, int n_in,
                              void* d_out, int out_size, void* d_ws, size_t ws_size,
                              hipStream_t stream) {
  const float* x     = (const float*)d_in[0];
  const int*   adj   = (const int*)  d_in[1];
  const float* W     = (const float*)d_in[2];
  const float* nw    = (const float*)d_in[5];
  const float* nb    = (const float*)d_in[6];
  const float* gamma = (const float*)d_in[7];
  const float* beta  = (const float*)d_in[8];
  float* out = (float*)d_out;

  char* ws = (char*)d_ws;
  U16*   h_lnB = (U16*)(ws);                            // 4 MB
  U16*   hTt   = (U16*)(ws + 4*1024*1024);              // 4 MB + 16 KB pad
  U16*   WT    = (U16*)(ws + 8*1024*1024 + 16*1024);    // 32 KB
  U32*   adjbT = (U32*)(ws + 9*1024*1024);              // 2 MB + 64 KB pad

  k0_combo<<<dim3(2112), dim3(256), 0, stream>>>(adj, adjbT, W, WT);
  k1_prep <<<dim3(256),  dim3(256), 0, stream>>>(x, WT, nw, nb, gamma, beta,
                                                 h_lnB, hTt);
  k2_main <<<dim3(256),  dim3(512), 0, stream>>>(adjbT, hTt, h_lnB, out);
}